// Round 9
// baseline (300.997 us; speedup 1.0000x reference)
//
#include <hip/hip_runtime.h>
#include <hip/hip_bf16.h>

typedef __bf16 bf16_t;
typedef _Float16 f16_t;
typedef __attribute__((ext_vector_type(8))) __bf16 bf16x8;
typedef __attribute__((ext_vector_type(8))) _Float16 f16x8;
typedef __attribute__((ext_vector_type(4))) _Float16 f16x4;
typedef __attribute__((ext_vector_type(4))) float f32x4;

#define SC_CAP 3072   // edges per scatter block (LDS-cached)

// ---------------- Phase A: single-pass GEMM y = x@w_pre + b_pre (f16) + col stats ----------------
__global__ __launch_bounds__(256) void k_pre_gemm(const float* __restrict__ x,
        const float* __restrict__ w_pre, const float* __restrict__ b_pre,
        f16_t* __restrict__ y, float* __restrict__ stats, int N) {
    __shared__ float ws[64][128];
    __shared__ float xs[64][64];
    __shared__ float red[8][2][128];
    const int tid = threadIdx.x;
    const int row0 = blockIdx.x * 64;

    for (int i = tid; i < 64 * 128; i += 256) ws[i >> 7][i & 127] = w_pre[i];
    {
        int r = tid >> 2, q = tid & 3;
        int rg = row0 + r; if (rg >= N) rg = N - 1;
        const float4* xr = (const float4*)(x + (size_t)rg * 64 + q * 16);
        float4* dr = (float4*)(&xs[r][q * 16]);
#pragma unroll
        for (int j = 0; j < 4; ++j) dr[j] = xr[j];
    }
    __syncthreads();

    const int rg8 = tid >> 5;
    const int c0 = (tid & 31) * 4;
    float acc[8][4] = {};
    for (int k = 0; k < 64; ++k) {
        float4 wv = *(const float4*)(&ws[k][c0]);
#pragma unroll
        for (int i = 0; i < 8; ++i) {
            float xv = xs[rg8 * 8 + i][k];
            acc[i][0] += xv * wv.x;
            acc[i][1] += xv * wv.y;
            acc[i][2] += xv * wv.z;
            acc[i][3] += xv * wv.w;
        }
    }

    float bc[4];
#pragma unroll
    for (int j = 0; j < 4; ++j) bc[j] = b_pre[c0 + j];
    float s1[4] = {}, s2[4] = {};
#pragma unroll
    for (int i = 0; i < 8; ++i) {
        int row = row0 + rg8 * 8 + i;
        if (row < N) {
            f16x4 o;
#pragma unroll
            for (int j = 0; j < 4; ++j) {
                float yv = acc[i][j] + bc[j];
                o[j] = (f16_t)yv;
                s1[j] += yv; s2[j] += yv * yv;
            }
            *(f16x4*)(y + (size_t)row * 128 + c0) = o;
        }
    }
#pragma unroll
    for (int j = 0; j < 4; ++j) {
        red[rg8][0][c0 + j] = s1[j];
        red[rg8][1][c0 + j] = s2[j];
    }
    __syncthreads();
    {
        int col = tid & 127, st = tid >> 7;
        float t = 0.f;
#pragma unroll
        for (int g = 0; g < 8; ++g) t += red[g][st][col];
        atomicAdd(&stats[st * 128 + col], t);
    }
}

__global__ void k_pre_finalize(const float* __restrict__ stats,
                               const float* __restrict__ g_pre, const float* __restrict__ be_pre,
                               float* __restrict__ ab, float invN) {
    int c = threadIdx.x;
    float mu = stats[c] * invN;
    float var = stats[128 + c] * invN - mu * mu;
    float a = g_pre[c] * rsqrtf(var + 1e-3f);
    ab[c] = a;
    ab[128 + c] = be_pre[c] - mu * a;
}

// ---------------- W'^T: wpT[n][k] ----------------
__global__ __launch_bounds__(256) void k_wprime(const float* __restrict__ w_cn,
        bf16_t* __restrict__ wpT) {
    int k = blockIdx.x;
    int c = threadIdx.x & 127, half = threadIdx.x >> 7;
    if (half == 0)
        wpT[c * 128 + k] = (bf16_t)(w_cn[k * 128 + c] - w_cn[(128 + k) * 128 + c]);
    else
        wpT[(128 + c) * 128 + k] = (bf16_t)(w_cn[(128 + k) * 128 + c]);
}

// ---------------- k_uv: fused BN+relu staging; [u|v] = h @ W' -> slice-major f16 [8][N][16] ----------------
__global__ __launch_bounds__(256) void k_uv(const f16_t* __restrict__ ypre,
        const float* __restrict__ ab, const bf16_t* __restrict__ wpT,
        const float* __restrict__ b_cn,
        f16_t* __restrict__ u, f16_t* __restrict__ v, int N, int ntiles) {
    __shared__ bf16_t at[64 * 136];
    __shared__ f16_t ot[64 * 264];
    __shared__ float a_s[128], b_s[128];

    const int tid = threadIdx.x;
    const int lane = tid & 63;
    const int wv = tid >> 6;
    const int n0 = wv * 64;
    const int l16 = lane & 15;
    const int lg = lane >> 4;

    if (tid < 128) { a_s[tid] = ab[tid]; b_s[tid] = ab[128 + tid]; }

    bf16x8 bfr[4][4];
#pragma unroll
    for (int s = 0; s < 4; ++s)
#pragma unroll
        for (int c = 0; c < 4; ++c)
            bfr[s][c] = *(const bf16x8*)(wpT + (n0 + 16 * c + l16) * 128 + 32 * s + 8 * lg);

    float bias[4];
#pragma unroll
    for (int c = 0; c < 4; ++c) {
        int n = n0 + 16 * c + l16;
        bias[c] = (n < 128) ? b_cn[n] : 0.f;
    }

    const int sr = tid >> 2, sq = tid & 3;
    __syncthreads();   // a_s/b_s ready before first staging

    for (int tile = blockIdx.x; tile < ntiles; tile += gridDim.x) {
        const int row0 = tile * 64;
        {
            int rg = row0 + sr; if (rg >= N) rg = N - 1;
            const f16_t* yr = ypre + (size_t)rg * 128 + sq * 32;
            bf16_t* dr = at + sr * 136 + sq * 32;
#pragma unroll
            for (int c4 = 0; c4 < 4; ++c4) {
                f16x8 yv = *(const f16x8*)(yr + c4 * 8);
                bf16x8 hv;
#pragma unroll
                for (int j = 0; j < 8; ++j) {
                    int col = sq * 32 + c4 * 8 + j;
                    hv[j] = (bf16_t)fmaxf(a_s[col] * (float)yv[j] + b_s[col], 0.f);
                }
                *(bf16x8*)(dr + c4 * 8) = hv;
            }
        }
        __syncthreads();

        f32x4 acc[4][4];
#pragma unroll
        for (int c = 0; c < 4; ++c) {
            f32x4 ini = {bias[c], bias[c], bias[c], bias[c]};
#pragma unroll
            for (int rt = 0; rt < 4; ++rt) acc[rt][c] = ini;
        }
#pragma unroll
        for (int s = 0; s < 4; ++s) {
            bf16x8 afr[4];
#pragma unroll
            for (int rt = 0; rt < 4; ++rt)
                afr[rt] = *(const bf16x8*)(at + (rt * 16 + l16) * 136 + 32 * s + 8 * lg);
#pragma unroll
            for (int rt = 0; rt < 4; ++rt)
#pragma unroll
                for (int c = 0; c < 4; ++c)
                    acc[rt][c] = __builtin_amdgcn_mfma_f32_16x16x32_bf16(afr[rt], bfr[s][c], acc[rt][c], 0, 0, 0);
        }

#pragma unroll
        for (int rt = 0; rt < 4; ++rt)
#pragma unroll
            for (int c = 0; c < 4; ++c) {
                int n = n0 + 16 * c + l16;
#pragma unroll
                for (int reg = 0; reg < 4; ++reg) {
                    int r = rt * 16 + lg * 4 + reg;
                    ot[r * 264 + n] = (f16_t)acc[rt][c][reg];
                }
            }
        __syncthreads();

        // copy out to slice-major [8][N][16]
#pragma unroll
        for (int it = 0; it < 8; ++it) {
            int r = wv * 16 + it * 2 + (lane >> 5);
            int cc = (lane & 31) * 8;
            int rg = row0 + r;
            if (rg < N) {
                f16x8 w8 = *(const f16x8*)(ot + r * 264 + cc);
                if (cc < 128) {
                    int sl = cc >> 4, col = cc & 15;
                    *(f16x8*)(u + ((size_t)sl * N + rg) * 16 + col) = w8;
                } else {
                    int cv = cc - 128;
                    int sl = cv >> 4, col = cv & 15;
                    *(f16x8*)(v + ((size_t)sl * N + rg) * 16 + col) = w8;
                }
            }
        }
    }
}

// ---------------- counting sort of edges by g = seg[src[e]] ----------------
__global__ __launch_bounds__(256) void k_hist(const int* __restrict__ src,
        const int* __restrict__ seg, int* __restrict__ gcnt, int E) {
    __shared__ int lh[512];
    int tid = threadIdx.x;
    for (int i = tid; i < 512; i += 256) lh[i] = 0;
    __syncthreads();
    for (int e = blockIdx.x * 256 + tid; e < E; e += gridDim.x * 256)
        atomicAdd(&lh[seg[src[e]]], 1);
    __syncthreads();
    for (int i = tid; i < 512; i += 256)
        if (lh[i]) atomicAdd(&gcnt[i], lh[i]);
}

__global__ __launch_bounds__(512) void k_scan(const int* __restrict__ gcnt,
        int* __restrict__ offs, int* __restrict__ cursor) {
    __shared__ int s[512];
    int tid = threadIdx.x;
    s[tid] = gcnt[tid];
    __syncthreads();
    for (int off = 1; off < 512; off <<= 1) {
        int v = (tid >= off) ? s[tid - off] : 0;
        __syncthreads();
        s[tid] += v;
        __syncthreads();
    }
    offs[tid + 1] = s[tid];
    int ex = tid ? s[tid - 1] : 0;
    if (tid == 0) offs[0] = 0;
    cursor[tid] = ex;
}

// ---------------- k_scatter: one pass, LDS-cached, u32-packed (needs N<65536) ----------------
__global__ __launch_bounds__(512) void k_scatter(const int* __restrict__ src,
        const int* __restrict__ dst, const int* __restrict__ seg,
        int* __restrict__ cursor, unsigned int* __restrict__ sorted, int E, int CH) {
    __shared__ int lh[512];
    __shared__ int lbase[512];
    __shared__ unsigned int pcache[SC_CAP];
    __shared__ unsigned short gcache[SC_CAP];
    const int tid = threadIdx.x;
    const int e0 = blockIdx.x * CH;
    const int e1 = min(E, e0 + CH);
    lh[tid] = 0;
    __syncthreads();
    for (int e = e0 + tid; e < e1; e += 512) {
        int si = src[e], di = dst[e];
        int g = seg[si];
        pcache[e - e0] = ((unsigned)si << 16) | (unsigned)di;
        gcache[e - e0] = (unsigned short)g;
        atomicAdd(&lh[g], 1);
    }
    __syncthreads();
    {
        int c = lh[tid];
        lbase[tid] = c ? atomicAdd(&cursor[tid], c) : 0;
        lh[tid] = 0;
    }
    __syncthreads();
    for (int e = e0 + tid; e < e1; e += 512) {
        int g = gcache[e - e0];
        int k = atomicAdd(&lh[g], 1);
        sorted[lbase[g] + k] = pcache[e - e0];
    }
}

// ---------------- k_agg_slice: block (g, s) owns 16-col slice s of graph g ----------------
// s = bid & 7 -> all blocks of slice s land on XCD s (bid%8 round-robin heuristic):
// per-XCD working set = u-slice + v-slice = 3.2 MB, L2-resident. No atomics, no memset.
__global__ __launch_bounds__(256) void k_agg_slice(const unsigned int* __restrict__ sorted,
        const int* __restrict__ offs, const f16_t* __restrict__ u,
        const f16_t* __restrict__ v, float* __restrict__ p, int N) {
    const int s = blockIdx.x & 7;
    const int g = blockIdx.x >> 3;
    const int s0 = offs[g], s1 = offs[g + 1];
    const int tid = threadIdx.x;
    const int lane = tid & 63;
    const int wv = tid >> 6;
    const int esub = lane >> 1;     // 32 edges per wave-iter
    const int c0 = (lane & 1) * 8;  // 8 cols per lane
    const f16_t* ug = u + (size_t)s * N * 16;
    const f16_t* vg = v + (size_t)s * N * 16;
    float acc[8] = {};
    for (int base = s0 + wv * 32; base < s1; base += 128) {
        int e = base + esub;
        if (e < s1) {
            unsigned pk = sorted[e];
            f16x8 uu = *(const f16x8*)(ug + (size_t)(pk >> 16) * 16 + c0);
            f16x8 vv = *(const f16x8*)(vg + (size_t)(pk & 0xffffu) * 16 + c0);
#pragma unroll
            for (int j = 0; j < 8; ++j)
                acc[j] += fmaxf((float)uu[j] + (float)vv[j], 0.f);
        }
    }
#pragma unroll
    for (int j = 0; j < 8; ++j) {
        acc[j] += __shfl_xor(acc[j], 2, 64);
        acc[j] += __shfl_xor(acc[j], 4, 64);
        acc[j] += __shfl_xor(acc[j], 8, 64);
        acc[j] += __shfl_xor(acc[j], 16, 64);
        acc[j] += __shfl_xor(acc[j], 32, 64);
    }
    __shared__ float red[4][2][8];
    if (lane < 2) {
#pragma unroll
        for (int j = 0; j < 8; ++j) red[wv][lane][j] = acc[j];
    }
    __syncthreads();
    if (tid < 16) {
        int hh = tid >> 3, j = tid & 7;
        float sum = red[0][hh][j] + red[1][hh][j] + red[2][hh][j] + red[3][hh][j];
        p[g * 128 + s * 16 + hh * 8 + j] = sum;   // exclusive owner: plain store
    }
}

// ---------------- Phase C: post MLP + BN + head ----------------
__global__ __launch_bounds__(256) void k_post_gemm(const float* __restrict__ p,
        const float* __restrict__ w_post, const float* __restrict__ b_post,
        float* __restrict__ y, float* __restrict__ stats) {
    int tid = threadIdx.x;
    int row0 = blockIdx.x * 16;
    int col = tid & 127, rg = tid >> 7;
    float acc[8] = {};
    for (int k = 0; k < 128; ++k) {
        float wv = w_post[k * 128 + col];
#pragma unroll
        for (int i = 0; i < 8; ++i) acc[i] += p[(row0 + rg * 8 + i) * 128 + k] * wv;
    }
    float b = b_post[col], s1 = 0.f, s2 = 0.f;
#pragma unroll
    for (int i = 0; i < 8; ++i) {
        float yv = acc[i] + b;
        y[(row0 + rg * 8 + i) * 128 + col] = yv;
        s1 += yv; s2 += yv * yv;
    }
    atomicAdd(&stats[col], s1);
    atomicAdd(&stats[128 + col], s2);
}

__global__ void k_post_finalize(const float* __restrict__ stats, const float* __restrict__ g_post,
                                const float* __restrict__ be_post, float* __restrict__ ab, float invG) {
    int c = threadIdx.x;
    float mu = stats[c] * invG;
    float var = stats[128 + c] * invG - mu * mu;
    float a = g_post[c] * rsqrtf(var + 1e-3f);
    ab[c] = a;
    ab[128 + c] = be_post[c] - mu * a;
}

__global__ __launch_bounds__(256) void k_out(const float* __restrict__ y,
        const float* __restrict__ ab, const float* __restrict__ w_out,
        const float* __restrict__ b_out, float* __restrict__ out) {
    int lane = threadIdx.x & 63;
    int wv = threadIdx.x >> 6;
    int row = blockIdx.x * 4 + wv;
    int c0 = lane * 2;
    float v = 0.f;
#pragma unroll
    for (int j = 0; j < 2; ++j) {
        int c = c0 + j;
        float t = fmaxf(ab[c] * y[row * 128 + c] + ab[128 + c], 0.f);
        v += t * w_out[c];
    }
#pragma unroll
    for (int m = 32; m >= 1; m >>= 1) v += __shfl_xor(v, m, 64);
    if (lane == 0) out[row] = 1.f / (1.f + expf(-(v + b_out[0])));
}

extern "C" void kernel_launch(void* const* d_in, const int* in_sizes, int n_in,
                              void* d_out, int out_size, void* d_ws, size_t ws_size,
                              hipStream_t stream) {
    const float* x      = (const float*)d_in[0];
    const int*   src    = (const int*)d_in[1];
    const int*   dst    = (const int*)d_in[2];
    const int*   seg    = (const int*)d_in[3];
    const float* w_pre  = (const float*)d_in[4];
    const float* b_pre  = (const float*)d_in[5];
    const float* g_pre  = (const float*)d_in[6];
    const float* be_pre = (const float*)d_in[7];
    const float* w_cn   = (const float*)d_in[8];
    const float* b_cn   = (const float*)d_in[9];
    const float* w_post = (const float*)d_in[10];
    const float* b_post = (const float*)d_in[11];
    const float* g_post = (const float*)d_in[12];
    const float* be_post= (const float*)d_in[13];
    const float* w_out  = (const float*)d_in[14];
    const float* b_out  = (const float*)d_in[15];
    const int E = in_sizes[1];
    const int N = in_sizes[3];
    const int G = out_size;

    char* ws = (char*)d_ws;
    float* stats_pre  = (float*)(ws + 0);        // zeroed each call
    float* stats_post = (float*)(ws + 1024);     // zeroed each call
    int*   gcnt       = (int*)(ws + 2048);       // zeroed each call
    float* ab_pre     = (float*)(ws + 4096);
    float* ab_post    = (float*)(ws + 5120);
    int*   offs       = (int*)(ws + 6144);
    int*   cursor     = (int*)(ws + 10240);
    bf16_t* wpT       = (bf16_t*)(ws + 12288);   // 64KB
    float* pbuf       = (float*)(ws + 131072);   // 256KB, fully written by k_agg_slice
    float* ybuf       = (float*)(ws + 131072 + 262144);
    size_t big0 = 1 << 20;
    size_t NB = (((size_t)N * 128 * 2) + 4095) & ~(size_t)4095;
    f16_t* ubuf = (f16_t*)(ws + big0);            // [8][N][16] f16
    f16_t* vbuf = (f16_t*)(ws + big0 + NB);       // [8][N][16] f16
    unsigned int* sorted = (unsigned int*)(ws + big0 + 2 * NB);
    f16_t* ypre  = (f16_t*)(ws + big0 + 3 * NB);
    (void)ws_size;

    // zero only stats + gcnt (4 KB); pbuf needs no memset (plain stores)
    (void)hipMemsetAsync(d_ws, 0, 4096, stream);

    int nb64 = (N + 63) / 64;
    k_pre_gemm<<<nb64, 256, 0, stream>>>(x, w_pre, b_pre, ypre, stats_pre, N);
    k_pre_finalize<<<1, 128, 0, stream>>>(stats_pre, g_pre, be_pre, ab_pre, 1.f / (float)N);
    k_wprime<<<128, 256, 0, stream>>>(w_cn, wpT);
    k_uv<<<256, 256, 0, stream>>>(ypre, ab_pre, wpT, b_cn, ubuf, vbuf, N, nb64);
    k_hist<<<512, 256, 0, stream>>>(src, seg, gcnt, E);
    k_scan<<<1, 512, 0, stream>>>(gcnt, offs, cursor);
    int nsc = (E + SC_CAP - 1) / SC_CAP;
    k_scatter<<<nsc, 512, 0, stream>>>(src, dst, seg, cursor, sorted, E, SC_CAP);
    k_agg_slice<<<8 * G, 256, 0, stream>>>(sorted, offs, ubuf, vbuf, pbuf, N);
    k_post_gemm<<<G / 16, 256, 0, stream>>>(pbuf, w_post, b_post, ybuf, stats_post);
    k_post_finalize<<<1, 128, 0, stream>>>(stats_post, g_post, be_post, ab_post, 1.f / (float)G);
    k_out<<<G / 4, 256, 0, stream>>>(ybuf, ab_post, w_out, b_out, (float*)d_out);
}

// Round 10
// 292.609 us; speedup vs baseline: 1.0287x; 1.0287x over previous
//
#include <hip/hip_runtime.h>
#include <hip/hip_bf16.h>

typedef __bf16 bf16_t;
typedef _Float16 f16_t;
typedef __attribute__((ext_vector_type(8))) __bf16 bf16x8;
typedef __attribute__((ext_vector_type(8))) _Float16 f16x8;
typedef __attribute__((ext_vector_type(4))) _Float16 f16x4;
typedef __attribute__((ext_vector_type(4))) float f32x4;

#define SC_CAP 3072   // edges per scatter block (LDS-cached)

// ---------------- Phase A: single-pass GEMM y = x@w_pre + b_pre (f16) + col stats ----------------
__global__ __launch_bounds__(256) void k_pre_gemm(const float* __restrict__ x,
        const float* __restrict__ w_pre, const float* __restrict__ b_pre,
        f16_t* __restrict__ y, float* __restrict__ stats, int N) {
    __shared__ float ws[64][128];
    __shared__ float xs[64][64];
    __shared__ float red[8][2][128];
    const int tid = threadIdx.x;
    const int row0 = blockIdx.x * 64;

    for (int i = tid; i < 64 * 128; i += 256) ws[i >> 7][i & 127] = w_pre[i];
    {
        int r = tid >> 2, q = tid & 3;
        int rg = row0 + r; if (rg >= N) rg = N - 1;
        const float4* xr = (const float4*)(x + (size_t)rg * 64 + q * 16);
        float4* dr = (float4*)(&xs[r][q * 16]);
#pragma unroll
        for (int j = 0; j < 4; ++j) dr[j] = xr[j];
    }
    __syncthreads();

    const int rg8 = tid >> 5;
    const int c0 = (tid & 31) * 4;
    float acc[8][4] = {};
    for (int k = 0; k < 64; ++k) {
        float4 wv = *(const float4*)(&ws[k][c0]);
#pragma unroll
        for (int i = 0; i < 8; ++i) {
            float xv = xs[rg8 * 8 + i][k];
            acc[i][0] += xv * wv.x;
            acc[i][1] += xv * wv.y;
            acc[i][2] += xv * wv.z;
            acc[i][3] += xv * wv.w;
        }
    }

    float bc[4];
#pragma unroll
    for (int j = 0; j < 4; ++j) bc[j] = b_pre[c0 + j];
    float s1[4] = {}, s2[4] = {};
#pragma unroll
    for (int i = 0; i < 8; ++i) {
        int row = row0 + rg8 * 8 + i;
        if (row < N) {
            f16x4 o;
#pragma unroll
            for (int j = 0; j < 4; ++j) {
                float yv = acc[i][j] + bc[j];
                o[j] = (f16_t)yv;
                s1[j] += yv; s2[j] += yv * yv;
            }
            *(f16x4*)(y + (size_t)row * 128 + c0) = o;
        }
    }
#pragma unroll
    for (int j = 0; j < 4; ++j) {
        red[rg8][0][c0 + j] = s1[j];
        red[rg8][1][c0 + j] = s2[j];
    }
    __syncthreads();
    {
        int col = tid & 127, st = tid >> 7;
        float t = 0.f;
#pragma unroll
        for (int g = 0; g < 8; ++g) t += red[g][st][col];
        atomicAdd(&stats[st * 128 + col], t);
    }
}

__global__ void k_pre_finalize(const float* __restrict__ stats,
                               const float* __restrict__ g_pre, const float* __restrict__ be_pre,
                               float* __restrict__ ab, float invN) {
    int c = threadIdx.x;
    float mu = stats[c] * invN;
    float var = stats[128 + c] * invN - mu * mu;
    float a = g_pre[c] * rsqrtf(var + 1e-3f);
    ab[c] = a;
    ab[128 + c] = be_pre[c] - mu * a;
}

// ---------------- W'^T: wpT[n][k] ----------------
__global__ __launch_bounds__(256) void k_wprime(const float* __restrict__ w_cn,
        bf16_t* __restrict__ wpT) {
    int k = blockIdx.x;
    int c = threadIdx.x & 127, half = threadIdx.x >> 7;
    if (half == 0)
        wpT[c * 128 + k] = (bf16_t)(w_cn[k * 128 + c] - w_cn[(128 + k) * 128 + c]);
    else
        wpT[(128 + c) * 128 + k] = (bf16_t)(w_cn[(128 + k) * 128 + c]);
}

// ---------------- k_uv: fused BN+relu staging; [u|v] = h @ W' -> slice-major f16 [8][N][16] ----------------
__global__ __launch_bounds__(256) void k_uv(const f16_t* __restrict__ ypre,
        const float* __restrict__ ab, const bf16_t* __restrict__ wpT,
        const float* __restrict__ b_cn,
        f16_t* __restrict__ u, f16_t* __restrict__ v, int N, int ntiles) {
    __shared__ bf16_t at[64 * 136];
    __shared__ f16_t ot[64 * 264];
    __shared__ float a_s[128], b_s[128];

    const int tid = threadIdx.x;
    const int lane = tid & 63;
    const int wv = tid >> 6;
    const int n0 = wv * 64;
    const int l16 = lane & 15;
    const int lg = lane >> 4;

    if (tid < 128) { a_s[tid] = ab[tid]; b_s[tid] = ab[128 + tid]; }

    bf16x8 bfr[4][4];
#pragma unroll
    for (int s = 0; s < 4; ++s)
#pragma unroll
        for (int c = 0; c < 4; ++c)
            bfr[s][c] = *(const bf16x8*)(wpT + (n0 + 16 * c + l16) * 128 + 32 * s + 8 * lg);

    float bias[4];
#pragma unroll
    for (int c = 0; c < 4; ++c) {
        int n = n0 + 16 * c + l16;
        bias[c] = (n < 128) ? b_cn[n] : 0.f;
    }

    const int sr = tid >> 2, sq = tid & 3;
    __syncthreads();   // a_s/b_s ready before first staging

    for (int tile = blockIdx.x; tile < ntiles; tile += gridDim.x) {
        const int row0 = tile * 64;
        {
            int rg = row0 + sr; if (rg >= N) rg = N - 1;
            const f16_t* yr = ypre + (size_t)rg * 128 + sq * 32;
            bf16_t* dr = at + sr * 136 + sq * 32;
#pragma unroll
            for (int c4 = 0; c4 < 4; ++c4) {
                f16x8 yv = *(const f16x8*)(yr + c4 * 8);
                bf16x8 hv;
#pragma unroll
                for (int j = 0; j < 8; ++j) {
                    int col = sq * 32 + c4 * 8 + j;
                    hv[j] = (bf16_t)fmaxf(a_s[col] * (float)yv[j] + b_s[col], 0.f);
                }
                *(bf16x8*)(dr + c4 * 8) = hv;
            }
        }
        __syncthreads();

        f32x4 acc[4][4];
#pragma unroll
        for (int c = 0; c < 4; ++c) {
            f32x4 ini = {bias[c], bias[c], bias[c], bias[c]};
#pragma unroll
            for (int rt = 0; rt < 4; ++rt) acc[rt][c] = ini;
        }
#pragma unroll
        for (int s = 0; s < 4; ++s) {
            bf16x8 afr[4];
#pragma unroll
            for (int rt = 0; rt < 4; ++rt)
                afr[rt] = *(const bf16x8*)(at + (rt * 16 + l16) * 136 + 32 * s + 8 * lg);
#pragma unroll
            for (int rt = 0; rt < 4; ++rt)
#pragma unroll
                for (int c = 0; c < 4; ++c)
                    acc[rt][c] = __builtin_amdgcn_mfma_f32_16x16x32_bf16(afr[rt], bfr[s][c], acc[rt][c], 0, 0, 0);
        }

#pragma unroll
        for (int rt = 0; rt < 4; ++rt)
#pragma unroll
            for (int c = 0; c < 4; ++c) {
                int n = n0 + 16 * c + l16;
#pragma unroll
                for (int reg = 0; reg < 4; ++reg) {
                    int r = rt * 16 + lg * 4 + reg;
                    ot[r * 264 + n] = (f16_t)acc[rt][c][reg];
                }
            }
        __syncthreads();

        // copy out to slice-major [8][N][16]
#pragma unroll
        for (int it = 0; it < 8; ++it) {
            int r = wv * 16 + it * 2 + (lane >> 5);
            int cc = (lane & 31) * 8;
            int rg = row0 + r;
            if (rg < N) {
                f16x8 w8 = *(const f16x8*)(ot + r * 264 + cc);
                if (cc < 128) {
                    int sl = cc >> 4, col = cc & 15;
                    *(f16x8*)(u + ((size_t)sl * N + rg) * 16 + col) = w8;
                } else {
                    int cv = cc - 128;
                    int sl = cv >> 4, col = cv & 15;
                    *(f16x8*)(v + ((size_t)sl * N + rg) * 16 + col) = w8;
                }
            }
        }
    }
}

// ---------------- counting sort of edges by g = seg[src[e]] ----------------
__global__ __launch_bounds__(256) void k_hist(const int* __restrict__ src,
        const int* __restrict__ seg, int* __restrict__ gcnt, int E) {
    __shared__ int lh[512];
    int tid = threadIdx.x;
    for (int i = tid; i < 512; i += 256) lh[i] = 0;
    __syncthreads();
    for (int e = blockIdx.x * 256 + tid; e < E; e += gridDim.x * 256)
        atomicAdd(&lh[seg[src[e]]], 1);
    __syncthreads();
    for (int i = tid; i < 512; i += 256)
        if (lh[i]) atomicAdd(&gcnt[i], lh[i]);
}

__global__ __launch_bounds__(512) void k_scan(const int* __restrict__ gcnt,
        int* __restrict__ offs, int* __restrict__ cursor) {
    __shared__ int s[512];
    int tid = threadIdx.x;
    s[tid] = gcnt[tid];
    __syncthreads();
    for (int off = 1; off < 512; off <<= 1) {
        int v = (tid >= off) ? s[tid - off] : 0;
        __syncthreads();
        s[tid] += v;
        __syncthreads();
    }
    offs[tid + 1] = s[tid];
    int ex = tid ? s[tid - 1] : 0;
    if (tid == 0) offs[0] = 0;
    cursor[tid] = ex;
}

// ---------------- k_scatter: one pass, LDS-cached, u32-packed (needs N<65536) ----------------
__global__ __launch_bounds__(512) void k_scatter(const int* __restrict__ src,
        const int* __restrict__ dst, const int* __restrict__ seg,
        int* __restrict__ cursor, unsigned int* __restrict__ sorted, int E, int CH) {
    __shared__ int lh[512];
    __shared__ int lbase[512];
    __shared__ unsigned int pcache[SC_CAP];
    __shared__ unsigned short gcache[SC_CAP];
    const int tid = threadIdx.x;
    const int e0 = blockIdx.x * CH;
    const int e1 = min(E, e0 + CH);
    lh[tid] = 0;
    __syncthreads();
    for (int e = e0 + tid; e < e1; e += 512) {
        int si = src[e], di = dst[e];
        int g = seg[si];
        pcache[e - e0] = ((unsigned)si << 16) | (unsigned)di;
        gcache[e - e0] = (unsigned short)g;
        atomicAdd(&lh[g], 1);
    }
    __syncthreads();
    {
        int c = lh[tid];
        lbase[tid] = c ? atomicAdd(&cursor[tid], c) : 0;
        lh[tid] = 0;
    }
    __syncthreads();
    for (int e = e0 + tid; e < e1; e += 512) {
        int g = gcache[e - e0];
        int k = atomicAdd(&lh[g], 1);
        sorted[lbase[g] + k] = pcache[e - e0];
    }
}

// ---------------- k_agg_slice: block (g, s) owns 16-col slice s of graph g ----------------
// s = bid & 7 -> slice s pinned to XCD s (bid%8 round-robin); per-XCD working set 3.2 MB L2-resident.
// Main loop: 2 independent edge streams, no branches -> loads hoisted, latency overlapped.
// Packed f16 add/relu (v_pk_*), f32 accumulate via fma_mix. No atomics.
__global__ __launch_bounds__(256) void k_agg_slice(const unsigned int* __restrict__ sorted,
        const int* __restrict__ offs, const f16_t* __restrict__ u,
        const f16_t* __restrict__ v, float* __restrict__ p, int N) {
    const int s = blockIdx.x & 7;
    const int g = blockIdx.x >> 3;
    const int s0 = offs[g], s1 = offs[g + 1];
    const int tid = threadIdx.x;
    const int lane = tid & 63;
    const int wv = tid >> 6;
    const int esub = lane >> 1;     // 32 edges per wave-chunk
    const int c0 = (lane & 1) * 8;  // 8 cols per lane
    const f16_t* ug = u + (size_t)s * N * 16 + c0;
    const f16_t* vg = v + (size_t)s * N * 16 + c0;
    const f16x8 zero = {};
    float acc[8] = {};

    int base = s0 + wv * 32;
    // main: streams A(base) and B(base+128), both chunks fully valid -> unguarded
    for (; base + 160 <= s1; base += 256) {
        unsigned pA = sorted[base + esub];
        unsigned pB = sorted[base + 128 + esub];
        f16x8 uA = *(const f16x8*)(ug + (size_t)(pA >> 16) * 16);
        f16x8 vA = *(const f16x8*)(vg + (size_t)(pA & 0xffffu) * 16);
        f16x8 uB = *(const f16x8*)(ug + (size_t)(pB >> 16) * 16);
        f16x8 vB = *(const f16x8*)(vg + (size_t)(pB & 0xffffu) * 16);
        f16x8 rA = __builtin_elementwise_max(uA + vA, zero);  // v_pk_add + v_pk_max
        f16x8 rB = __builtin_elementwise_max(uB + vB, zero);
#pragma unroll
        for (int j = 0; j < 8; ++j) acc[j] += (float)rA[j];   // v_fma_mix path
#pragma unroll
        for (int j = 0; j < 8; ++j) acc[j] += (float)rB[j];
    }
    // tail: guarded single-stream
    for (; base < s1; base += 128) {
        int e = base + esub;
        if (e < s1) {
            unsigned pk = sorted[e];
            f16x8 uu = *(const f16x8*)(ug + (size_t)(pk >> 16) * 16);
            f16x8 vv = *(const f16x8*)(vg + (size_t)(pk & 0xffffu) * 16);
            f16x8 r = __builtin_elementwise_max(uu + vv, zero);
#pragma unroll
            for (int j = 0; j < 8; ++j) acc[j] += (float)r[j];
        }
    }

#pragma unroll
    for (int j = 0; j < 8; ++j) {
        acc[j] += __shfl_xor(acc[j], 2, 64);
        acc[j] += __shfl_xor(acc[j], 4, 64);
        acc[j] += __shfl_xor(acc[j], 8, 64);
        acc[j] += __shfl_xor(acc[j], 16, 64);
        acc[j] += __shfl_xor(acc[j], 32, 64);
    }
    __shared__ float red[4][2][8];
    if (lane < 2) {
#pragma unroll
        for (int j = 0; j < 8; ++j) red[wv][lane][j] = acc[j];
    }
    __syncthreads();
    if (tid < 16) {
        int hh = tid >> 3, j = tid & 7;
        float sum = red[0][hh][j] + red[1][hh][j] + red[2][hh][j] + red[3][hh][j];
        p[g * 128 + s * 16 + hh * 8 + j] = sum;   // exclusive owner: plain store
    }
}

// ---------------- Phase C: post MLP + BN + head ----------------
__global__ __launch_bounds__(256) void k_post_gemm(const float* __restrict__ p,
        const float* __restrict__ w_post, const float* __restrict__ b_post,
        float* __restrict__ y, float* __restrict__ stats) {
    int tid = threadIdx.x;
    int row0 = blockIdx.x * 16;
    int col = tid & 127, rg = tid >> 7;
    float acc[8] = {};
    for (int k = 0; k < 128; ++k) {
        float wv = w_post[k * 128 + col];
#pragma unroll
        for (int i = 0; i < 8; ++i) acc[i] += p[(row0 + rg * 8 + i) * 128 + k] * wv;
    }
    float b = b_post[col], s1 = 0.f, s2 = 0.f;
#pragma unroll
    for (int i = 0; i < 8; ++i) {
        float yv = acc[i] + b;
        y[(row0 + rg * 8 + i) * 128 + col] = yv;
        s1 += yv; s2 += yv * yv;
    }
    atomicAdd(&stats[col], s1);
    atomicAdd(&stats[128 + col], s2);
}

__global__ void k_post_finalize(const float* __restrict__ stats, const float* __restrict__ g_post,
                                const float* __restrict__ be_post, float* __restrict__ ab, float invG) {
    int c = threadIdx.x;
    float mu = stats[c] * invG;
    float var = stats[128 + c] * invG - mu * mu;
    float a = g_post[c] * rsqrtf(var + 1e-3f);
    ab[c] = a;
    ab[128 + c] = be_post[c] - mu * a;
}

__global__ __launch_bounds__(256) void k_out(const float* __restrict__ y,
        const float* __restrict__ ab, const float* __restrict__ w_out,
        const float* __restrict__ b_out, float* __restrict__ out) {
    int lane = threadIdx.x & 63;
    int wv = threadIdx.x >> 6;
    int row = blockIdx.x * 4 + wv;
    int c0 = lane * 2;
    float v = 0.f;
#pragma unroll
    for (int j = 0; j < 2; ++j) {
        int c = c0 + j;
        float t = fmaxf(ab[c] * y[row * 128 + c] + ab[128 + c], 0.f);
        v += t * w_out[c];
    }
#pragma unroll
    for (int m = 32; m >= 1; m >>= 1) v += __shfl_xor(v, m, 64);
    if (lane == 0) out[row] = 1.f / (1.f + expf(-(v + b_out[0])));
}

extern "C" void kernel_launch(void* const* d_in, const int* in_sizes, int n_in,
                              void* d_out, int out_size, void* d_ws, size_t ws_size,
                              hipStream_t stream) {
    const float* x      = (const float*)d_in[0];
    const int*   src    = (const int*)d_in[1];
    const int*   dst    = (const int*)d_in[2];
    const int*   seg    = (const int*)d_in[3];
    const float* w_pre  = (const float*)d_in[4];
    const float* b_pre  = (const float*)d_in[5];
    const float* g_pre  = (const float*)d_in[6];
    const float* be_pre = (const float*)d_in[7];
    const float* w_cn   = (const float*)d_in[8];
    const float* b_cn   = (const float*)d_in[9];
    const float* w_post = (const float*)d_in[10];
    const float* b_post = (const float*)d_in[11];
    const float* g_post = (const float*)d_in[12];
    const float* be_post= (const float*)d_in[13];
    const float* w_out  = (const float*)d_in[14];
    const float* b_out  = (const float*)d_in[15];
    const int E = in_sizes[1];
    const int N = in_sizes[3];
    const int G = out_size;

    char* ws = (char*)d_ws;
    float* stats_pre  = (float*)(ws + 0);        // zeroed each call
    float* stats_post = (float*)(ws + 1024);     // zeroed each call
    int*   gcnt       = (int*)(ws + 2048);       // zeroed each call
    float* ab_pre     = (float*)(ws + 4096);
    float* ab_post    = (float*)(ws + 5120);
    int*   offs       = (int*)(ws + 6144);
    int*   cursor     = (int*)(ws + 10240);
    bf16_t* wpT       = (bf16_t*)(ws + 12288);   // 64KB
    float* pbuf       = (float*)(ws + 131072);   // 256KB, fully written by k_agg_slice
    float* ybuf       = (float*)(ws + 131072 + 262144);
    size_t big0 = 1 << 20;
    size_t NB = (((size_t)N * 128 * 2) + 4095) & ~(size_t)4095;
    f16_t* ubuf = (f16_t*)(ws + big0);            // [8][N][16] f16
    f16_t* vbuf = (f16_t*)(ws + big0 + NB);       // [8][N][16] f16
    unsigned int* sorted = (unsigned int*)(ws + big0 + 2 * NB);
    f16_t* ypre  = (f16_t*)(ws + big0 + 3 * NB);
    (void)ws_size;

    // zero only stats + gcnt (4 KB)
    (void)hipMemsetAsync(d_ws, 0, 4096, stream);

    int nb64 = (N + 63) / 64;
    k_pre_gemm<<<nb64, 256, 0, stream>>>(x, w_pre, b_pre, ypre, stats_pre, N);
    k_pre_finalize<<<1, 128, 0, stream>>>(stats_pre, g_pre, be_pre, ab_pre, 1.f / (float)N);
    k_wprime<<<128, 256, 0, stream>>>(w_cn, wpT);
    k_uv<<<256, 256, 0, stream>>>(ypre, ab_pre, wpT, b_cn, ubuf, vbuf, N, nb64);
    k_hist<<<512, 256, 0, stream>>>(src, seg, gcnt, E);
    k_scan<<<1, 512, 0, stream>>>(gcnt, offs, cursor);
    int nsc = (E + SC_CAP - 1) / SC_CAP;
    k_scatter<<<nsc, 512, 0, stream>>>(src, dst, seg, cursor, sorted, E, SC_CAP);
    k_agg_slice<<<8 * G, 256, 0, stream>>>(sorted, offs, ubuf, vbuf, pbuf, N);
    k_post_gemm<<<G / 16, 256, 0, stream>>>(pbuf, w_post, b_post, ybuf, stats_post);
    k_post_finalize<<<1, 128, 0, stream>>>(stats_post, g_post, be_post, ab_post, 1.f / (float)G);
    k_out<<<G / 4, 256, 0, stream>>>(ybuf, ab_post, w_out, b_out, (float*)d_out);
}

// Round 11
// 275.655 us; speedup vs baseline: 1.0919x; 1.0615x over previous
//
#include <hip/hip_runtime.h>
#include <hip/hip_bf16.h>

typedef __bf16 bf16_t;
typedef _Float16 f16_t;
typedef __attribute__((ext_vector_type(8))) __bf16 bf16x8;
typedef __attribute__((ext_vector_type(8))) _Float16 f16x8;
typedef __attribute__((ext_vector_type(4))) _Float16 f16x4;
typedef __attribute__((ext_vector_type(4))) float f32x4;

#define SC_CAP 3072   // edges per scatter block (LDS-cached)
#define MAXNR 512     // max graph node-rows staged in LDS (fallback above)

// ---------------- Phase A: single-pass GEMM y = x@w_pre + b_pre (f16) + col stats ----------------
__global__ __launch_bounds__(256) void k_pre_gemm(const float* __restrict__ x,
        const float* __restrict__ w_pre, const float* __restrict__ b_pre,
        f16_t* __restrict__ y, float* __restrict__ stats, int N) {
    __shared__ float ws[64][128];
    __shared__ float xs[64][64];
    __shared__ float red[8][2][128];
    const int tid = threadIdx.x;
    const int row0 = blockIdx.x * 64;

    for (int i = tid; i < 64 * 128; i += 256) ws[i >> 7][i & 127] = w_pre[i];
    {
        int r = tid >> 2, q = tid & 3;
        int rg = row0 + r; if (rg >= N) rg = N - 1;
        const float4* xr = (const float4*)(x + (size_t)rg * 64 + q * 16);
        float4* dr = (float4*)(&xs[r][q * 16]);
#pragma unroll
        for (int j = 0; j < 4; ++j) dr[j] = xr[j];
    }
    __syncthreads();

    const int rg8 = tid >> 5;
    const int c0 = (tid & 31) * 4;
    float acc[8][4] = {};
    for (int k = 0; k < 64; ++k) {
        float4 wv = *(const float4*)(&ws[k][c0]);
#pragma unroll
        for (int i = 0; i < 8; ++i) {
            float xv = xs[rg8 * 8 + i][k];
            acc[i][0] += xv * wv.x;
            acc[i][1] += xv * wv.y;
            acc[i][2] += xv * wv.z;
            acc[i][3] += xv * wv.w;
        }
    }

    float bc[4];
#pragma unroll
    for (int j = 0; j < 4; ++j) bc[j] = b_pre[c0 + j];
    float s1[4] = {}, s2[4] = {};
#pragma unroll
    for (int i = 0; i < 8; ++i) {
        int row = row0 + rg8 * 8 + i;
        if (row < N) {
            f16x4 o;
#pragma unroll
            for (int j = 0; j < 4; ++j) {
                float yv = acc[i][j] + bc[j];
                o[j] = (f16_t)yv;
                s1[j] += yv; s2[j] += yv * yv;
            }
            *(f16x4*)(y + (size_t)row * 128 + c0) = o;
        }
    }
#pragma unroll
    for (int j = 0; j < 4; ++j) {
        red[rg8][0][c0 + j] = s1[j];
        red[rg8][1][c0 + j] = s2[j];
    }
    __syncthreads();
    {
        int col = tid & 127, st = tid >> 7;
        float t = 0.f;
#pragma unroll
        for (int g = 0; g < 8; ++g) t += red[g][st][col];
        atomicAdd(&stats[st * 128 + col], t);
    }
}

// ---------------- W'^T: wpT[n][k] ----------------
__global__ __launch_bounds__(256) void k_wprime(const float* __restrict__ w_cn,
        bf16_t* __restrict__ wpT) {
    int k = blockIdx.x;
    int c = threadIdx.x & 127, half = threadIdx.x >> 7;
    if (half == 0)
        wpT[c * 128 + k] = (bf16_t)(w_cn[k * 128 + c] - w_cn[(128 + k) * 128 + c]);
    else
        wpT[(128 + c) * 128 + k] = (bf16_t)(w_cn[(128 + k) * 128 + c]);
}

// ---------------- k_uv: BN folded from stats; [u|v] = h @ W' -> slice-major f16 [8][N][16] ----------------
__global__ __launch_bounds__(256) void k_uv(const f16_t* __restrict__ ypre,
        const float* __restrict__ stats, const float* __restrict__ g_pre,
        const float* __restrict__ be_pre, const bf16_t* __restrict__ wpT,
        const float* __restrict__ b_cn,
        f16_t* __restrict__ u, f16_t* __restrict__ v, int N, int ntiles, float invN) {
    __shared__ bf16_t at[64 * 136];
    __shared__ f16_t ot[64 * 264];
    __shared__ float a_s[128], b_s[128];

    const int tid = threadIdx.x;
    const int lane = tid & 63;
    const int wv = tid >> 6;
    const int n0 = wv * 64;
    const int l16 = lane & 15;
    const int lg = lane >> 4;

    if (tid < 128) {
        float mu = stats[tid] * invN;
        float var = stats[128 + tid] * invN - mu * mu;
        float a = g_pre[tid] * rsqrtf(var + 1e-3f);
        a_s[tid] = a;
        b_s[tid] = be_pre[tid] - mu * a;
    }

    bf16x8 bfr[4][4];
#pragma unroll
    for (int s = 0; s < 4; ++s)
#pragma unroll
        for (int c = 0; c < 4; ++c)
            bfr[s][c] = *(const bf16x8*)(wpT + (n0 + 16 * c + l16) * 128 + 32 * s + 8 * lg);

    float bias[4];
#pragma unroll
    for (int c = 0; c < 4; ++c) {
        int n = n0 + 16 * c + l16;
        bias[c] = (n < 128) ? b_cn[n] : 0.f;
    }

    const int sr = tid >> 2, sq = tid & 3;
    __syncthreads();   // a_s/b_s ready before first staging

    for (int tile = blockIdx.x; tile < ntiles; tile += gridDim.x) {
        const int row0 = tile * 64;
        {
            int rg = row0 + sr; if (rg >= N) rg = N - 1;
            const f16_t* yr = ypre + (size_t)rg * 128 + sq * 32;
            bf16_t* dr = at + sr * 136 + sq * 32;
#pragma unroll
            for (int c4 = 0; c4 < 4; ++c4) {
                f16x8 yv = *(const f16x8*)(yr + c4 * 8);
                bf16x8 hv;
#pragma unroll
                for (int j = 0; j < 8; ++j) {
                    int col = sq * 32 + c4 * 8 + j;
                    hv[j] = (bf16_t)fmaxf(a_s[col] * (float)yv[j] + b_s[col], 0.f);
                }
                *(bf16x8*)(dr + c4 * 8) = hv;
            }
        }
        __syncthreads();

        f32x4 acc[4][4];
#pragma unroll
        for (int c = 0; c < 4; ++c) {
            f32x4 ini = {bias[c], bias[c], bias[c], bias[c]};
#pragma unroll
            for (int rt = 0; rt < 4; ++rt) acc[rt][c] = ini;
        }
#pragma unroll
        for (int s = 0; s < 4; ++s) {
            bf16x8 afr[4];
#pragma unroll
            for (int rt = 0; rt < 4; ++rt)
                afr[rt] = *(const bf16x8*)(at + (rt * 16 + l16) * 136 + 32 * s + 8 * lg);
#pragma unroll
            for (int rt = 0; rt < 4; ++rt)
#pragma unroll
                for (int c = 0; c < 4; ++c)
                    acc[rt][c] = __builtin_amdgcn_mfma_f32_16x16x32_bf16(afr[rt], bfr[s][c], acc[rt][c], 0, 0, 0);
        }

#pragma unroll
        for (int rt = 0; rt < 4; ++rt)
#pragma unroll
            for (int c = 0; c < 4; ++c) {
                int n = n0 + 16 * c + l16;
#pragma unroll
                for (int reg = 0; reg < 4; ++reg) {
                    int r = rt * 16 + lg * 4 + reg;
                    ot[r * 264 + n] = (f16_t)acc[rt][c][reg];
                }
            }
        __syncthreads();

        // copy out to slice-major [8][N][16]
#pragma unroll
        for (int it = 0; it < 8; ++it) {
            int r = wv * 16 + it * 2 + (lane >> 5);
            int cc = (lane & 31) * 8;
            int rg = row0 + r;
            if (rg < N) {
                f16x8 w8 = *(const f16x8*)(ot + r * 264 + cc);
                if (cc < 128) {
                    int sl = cc >> 4, col = cc & 15;
                    *(f16x8*)(u + ((size_t)sl * N + rg) * 16 + col) = w8;
                } else {
                    int cv = cc - 128;
                    int sl = cv >> 4, col = cv & 15;
                    *(f16x8*)(v + ((size_t)sl * N + rg) * 16 + col) = w8;
                }
            }
        }
    }
}

// ---------------- counting sort of edges by g = seg[src[e]] ----------------
__global__ __launch_bounds__(256) void k_hist(const int* __restrict__ src,
        const int* __restrict__ seg, int* __restrict__ gcnt, int E) {
    __shared__ int lh[512];
    int tid = threadIdx.x;
    for (int i = tid; i < 512; i += 256) lh[i] = 0;
    __syncthreads();
    for (int e = blockIdx.x * 256 + tid; e < E; e += gridDim.x * 256)
        atomicAdd(&lh[seg[src[e]]], 1);
    __syncthreads();
    for (int i = tid; i < 512; i += 256)
        if (lh[i]) atomicAdd(&gcnt[i], lh[i]);
}

__global__ __launch_bounds__(512) void k_scan(const int* __restrict__ gcnt,
        int* __restrict__ offs, int* __restrict__ cursor) {
    __shared__ int s[512];
    int tid = threadIdx.x;
    s[tid] = gcnt[tid];
    __syncthreads();
    for (int off = 1; off < 512; off <<= 1) {
        int v = (tid >= off) ? s[tid - off] : 0;
        __syncthreads();
        s[tid] += v;
        __syncthreads();
    }
    offs[tid + 1] = s[tid];
    int ex = tid ? s[tid - 1] : 0;
    if (tid == 0) offs[0] = 0;
    cursor[tid] = ex;
}

// ---------------- node_off[g] = first node row of graph g (seg sorted) ----------------
__global__ __launch_bounds__(256) void k_nodeoff(const int* __restrict__ seg,
        int* __restrict__ node_off, int N, int G) {
    int i = blockIdx.x * 256 + threadIdx.x;
    if (i >= N) return;
    int s = seg[i];
    int prev = (i == 0) ? -1 : seg[i - 1];
    for (int g = prev + 1; g <= s; ++g) node_off[g] = i;
    if (i == N - 1)
        for (int g = s + 1; g <= G; ++g) node_off[g] = N;
}

// ---------------- k_scatter: one pass, LDS-cached, u32-packed (needs N<65536) ----------------
__global__ __launch_bounds__(512) void k_scatter(const int* __restrict__ src,
        const int* __restrict__ dst, const int* __restrict__ seg,
        int* __restrict__ cursor, unsigned int* __restrict__ sorted, int E, int CH) {
    __shared__ int lh[512];
    __shared__ int lbase[512];
    __shared__ unsigned int pcache[SC_CAP];
    __shared__ unsigned short gcache[SC_CAP];
    const int tid = threadIdx.x;
    const int e0 = blockIdx.x * CH;
    const int e1 = min(E, e0 + CH);
    lh[tid] = 0;
    __syncthreads();
    for (int e = e0 + tid; e < e1; e += 512) {
        int si = src[e], di = dst[e];
        int g = seg[si];
        pcache[e - e0] = ((unsigned)si << 16) | (unsigned)di;
        gcache[e - e0] = (unsigned short)g;
        atomicAdd(&lh[g], 1);
    }
    __syncthreads();
    {
        int c = lh[tid];
        lbase[tid] = c ? atomicAdd(&cursor[tid], c) : 0;
        lh[tid] = 0;
    }
    __syncthreads();
    for (int e = e0 + tid; e < e1; e += 512) {
        int g = gcache[e - e0];
        int k = atomicAdd(&lh[g], 1);
        sorted[lbase[g] + k] = pcache[e - e0];
    }
}

// ---------------- k_agg_slice: block (g,s); u staged in LDS (graph rows contiguous) ----------------
// Slice s pinned to XCD s via bid&7; v-slice (1.6MB) L2-resident; u read from LDS (stride 40B).
// 3 independent edge streams hide v L2-hit latency. No atomics.
__global__ __launch_bounds__(256) void k_agg_slice(const unsigned int* __restrict__ sorted,
        const int* __restrict__ offs, const int* __restrict__ node_off,
        const f16_t* __restrict__ u, const f16_t* __restrict__ v,
        float* __restrict__ p, int N) {
    const int s = blockIdx.x & 7;
    const int g = blockIdx.x >> 3;
    const int s0 = offs[g], s1 = offs[g + 1];
    const int r0 = node_off[g];
    const int nr = node_off[g + 1] - r0;
    const int tid = threadIdx.x;
    const int lane = tid & 63;
    const int wv = tid >> 6;
    const int esub = lane >> 1;     // 32 edges per wave-chunk
    const int c0 = (lane & 1) * 8;  // 8 cols per lane
    const f16_t* ug = u + (size_t)s * N * 16;
    const f16_t* vg = v + (size_t)s * N * 16 + c0;
    const f16x8 zero = {};
    float acc[8] = {};

    __shared__ f16_t ulds[MAXNR * 20];   // row stride 20 f16 = 40B (bank spread)
    __shared__ float red[4][2][8];

    if (nr <= MAXNR) {
        // stage u rows [r0, r0+nr): contiguous global -> LDS
        for (int i = tid; i < nr * 2; i += 256) {
            int row = i >> 1, h = (i & 1) * 8;
            const f16_t* sp = ug + (size_t)(r0 + row) * 16 + h;
            f16_t* dp = ulds + row * 20 + h;
            *(f16x4*)(dp) = *(const f16x4*)(sp);
            *(f16x4*)(dp + 4) = *(const f16x4*)(sp + 4);
        }
        __syncthreads();

        int base = s0 + wv * 32;
        for (; base + 288 <= s1; base += 384) {   // 3 streams, unguarded
            unsigned pA = sorted[base + esub];
            unsigned pB = sorted[base + 128 + esub];
            unsigned pC = sorted[base + 256 + esub];
            f16x8 vA = *(const f16x8*)(vg + (size_t)(pA & 0xffffu) * 16);
            f16x8 vB = *(const f16x8*)(vg + (size_t)(pB & 0xffffu) * 16);
            f16x8 vC = *(const f16x8*)(vg + (size_t)(pC & 0xffffu) * 16);
            int lA = ((int)(pA >> 16) - r0) * 20 + c0;
            int lB = ((int)(pB >> 16) - r0) * 20 + c0;
            int lC = ((int)(pC >> 16) - r0) * 20 + c0;
            f16x4 a0 = *(const f16x4*)(ulds + lA), a1 = *(const f16x4*)(ulds + lA + 4);
            f16x4 b0 = *(const f16x4*)(ulds + lB), b1 = *(const f16x4*)(ulds + lB + 4);
            f16x4 c0v = *(const f16x4*)(ulds + lC), c1 = *(const f16x4*)(ulds + lC + 4);
            f16x8 uA = {a0[0], a0[1], a0[2], a0[3], a1[0], a1[1], a1[2], a1[3]};
            f16x8 uB = {b0[0], b0[1], b0[2], b0[3], b1[0], b1[1], b1[2], b1[3]};
            f16x8 uC = {c0v[0], c0v[1], c0v[2], c0v[3], c1[0], c1[1], c1[2], c1[3]};
            f16x8 rA = __builtin_elementwise_max(uA + vA, zero);
            f16x8 rB = __builtin_elementwise_max(uB + vB, zero);
            f16x8 rC = __builtin_elementwise_max(uC + vC, zero);
#pragma unroll
            for (int j = 0; j < 8; ++j) acc[j] += (float)rA[j];
#pragma unroll
            for (int j = 0; j < 8; ++j) acc[j] += (float)rB[j];
#pragma unroll
            for (int j = 0; j < 8; ++j) acc[j] += (float)rC[j];
        }
        for (; base < s1; base += 128) {          // guarded tail
            int e = base + esub;
            if (e < s1) {
                unsigned pk = sorted[e];
                f16x8 vv = *(const f16x8*)(vg + (size_t)(pk & 0xffffu) * 16);
                int l = ((int)(pk >> 16) - r0) * 20 + c0;
                f16x4 t0 = *(const f16x4*)(ulds + l), t1 = *(const f16x4*)(ulds + l + 4);
                f16x8 uu = {t0[0], t0[1], t0[2], t0[3], t1[0], t1[1], t1[2], t1[3]};
                f16x8 r = __builtin_elementwise_max(uu + vv, zero);
#pragma unroll
                for (int j = 0; j < 8; ++j) acc[j] += (float)r[j];
            }
        }
    } else {
        // fallback: global u gather (2 streams)
        const f16_t* ugc = ug + c0;
        int base = s0 + wv * 32;
        for (; base + 160 <= s1; base += 256) {
            unsigned pA = sorted[base + esub];
            unsigned pB = sorted[base + 128 + esub];
            f16x8 uA = *(const f16x8*)(ugc + (size_t)(pA >> 16) * 16);
            f16x8 vA = *(const f16x8*)(vg + (size_t)(pA & 0xffffu) * 16);
            f16x8 uB = *(const f16x8*)(ugc + (size_t)(pB >> 16) * 16);
            f16x8 vB = *(const f16x8*)(vg + (size_t)(pB & 0xffffu) * 16);
            f16x8 rA = __builtin_elementwise_max(uA + vA, zero);
            f16x8 rB = __builtin_elementwise_max(uB + vB, zero);
#pragma unroll
            for (int j = 0; j < 8; ++j) acc[j] += (float)rA[j];
#pragma unroll
            for (int j = 0; j < 8; ++j) acc[j] += (float)rB[j];
        }
        for (; base < s1; base += 128) {
            int e = base + esub;
            if (e < s1) {
                unsigned pk = sorted[e];
                f16x8 uu = *(const f16x8*)(ugc + (size_t)(pk >> 16) * 16);
                f16x8 vv = *(const f16x8*)(vg + (size_t)(pk & 0xffffu) * 16);
                f16x8 r = __builtin_elementwise_max(uu + vv, zero);
#pragma unroll
                for (int j = 0; j < 8; ++j) acc[j] += (float)r[j];
            }
        }
    }

#pragma unroll
    for (int j = 0; j < 8; ++j) {
        acc[j] += __shfl_xor(acc[j], 2, 64);
        acc[j] += __shfl_xor(acc[j], 4, 64);
        acc[j] += __shfl_xor(acc[j], 8, 64);
        acc[j] += __shfl_xor(acc[j], 16, 64);
        acc[j] += __shfl_xor(acc[j], 32, 64);
    }
    if (lane < 2) {
#pragma unroll
        for (int j = 0; j < 8; ++j) red[wv][lane][j] = acc[j];
    }
    __syncthreads();
    if (tid < 16) {
        int hh = tid >> 3, j = tid & 7;
        float sum = red[0][hh][j] + red[1][hh][j] + red[2][hh][j] + red[3][hh][j];
        p[g * 128 + s * 16 + hh * 8 + j] = sum;   // exclusive owner: plain store
    }
}

// ---------------- Phase C: post MLP + BN + head ----------------
__global__ __launch_bounds__(256) void k_post_gemm(const float* __restrict__ p,
        const float* __restrict__ w_post, const float* __restrict__ b_post,
        float* __restrict__ y, float* __restrict__ stats) {
    int tid = threadIdx.x;
    int row0 = blockIdx.x * 16;
    int col = tid & 127, rg = tid >> 7;
    float acc[8] = {};
    for (int k = 0; k < 128; ++k) {
        float wv = w_post[k * 128 + col];
#pragma unroll
        for (int i = 0; i < 8; ++i) acc[i] += p[(row0 + rg * 8 + i) * 128 + k] * wv;
    }
    float b = b_post[col], s1 = 0.f, s2 = 0.f;
#pragma unroll
    for (int i = 0; i < 8; ++i) {
        float yv = acc[i] + b;
        y[(row0 + rg * 8 + i) * 128 + col] = yv;
        s1 += yv; s2 += yv * yv;
    }
    atomicAdd(&stats[col], s1);
    atomicAdd(&stats[128 + col], s2);
}

// BN fold computed per-block from stats; then relu, head dot, sigmoid
__global__ __launch_bounds__(256) void k_out(const float* __restrict__ y,
        const float* __restrict__ stats, const float* __restrict__ g_post,
        const float* __restrict__ be_post, const float* __restrict__ w_out,
        const float* __restrict__ b_out, float* __restrict__ out, float invG) {
    __shared__ float a_s[128], b_s[128];
    int tid = threadIdx.x;
    if (tid < 128) {
        float mu = stats[tid] * invG;
        float var = stats[128 + tid] * invG - mu * mu;
        float a = g_post[tid] * rsqrtf(var + 1e-3f);
        a_s[tid] = a;
        b_s[tid] = be_post[tid] - mu * a;
    }
    __syncthreads();
    int lane = tid & 63;
    int wv = tid >> 6;
    int row = blockIdx.x * 4 + wv;
    int c0 = lane * 2;
    float v = 0.f;
#pragma unroll
    for (int j = 0; j < 2; ++j) {
        int c = c0 + j;
        float t = fmaxf(a_s[c] * y[row * 128 + c] + b_s[c], 0.f);
        v += t * w_out[c];
    }
#pragma unroll
    for (int m = 32; m >= 1; m >>= 1) v += __shfl_xor(v, m, 64);
    if (lane == 0) out[row] = 1.f / (1.f + expf(-(v + b_out[0])));
}

extern "C" void kernel_launch(void* const* d_in, const int* in_sizes, int n_in,
                              void* d_out, int out_size, void* d_ws, size_t ws_size,
                              hipStream_t stream) {
    const float* x      = (const float*)d_in[0];
    const int*   src    = (const int*)d_in[1];
    const int*   dst    = (const int*)d_in[2];
    const int*   seg    = (const int*)d_in[3];
    const float* w_pre  = (const float*)d_in[4];
    const float* b_pre  = (const float*)d_in[5];
    const float* g_pre  = (const float*)d_in[6];
    const float* be_pre = (const float*)d_in[7];
    const float* w_cn   = (const float*)d_in[8];
    const float* b_cn   = (const float*)d_in[9];
    const float* w_post = (const float*)d_in[10];
    const float* b_post = (const float*)d_in[11];
    const float* g_post = (const float*)d_in[12];
    const float* be_post= (const float*)d_in[13];
    const float* w_out  = (const float*)d_in[14];
    const float* b_out  = (const float*)d_in[15];
    const int E = in_sizes[1];
    const int N = in_sizes[3];
    const int G = out_size;

    char* ws = (char*)d_ws;
    float* stats_pre  = (float*)(ws + 0);        // zeroed each call
    float* stats_post = (float*)(ws + 1024);     // zeroed each call
    int*   gcnt       = (int*)(ws + 2048);       // zeroed each call
    int*   offs       = (int*)(ws + 4096);       // 513 ints
    int*   cursor     = (int*)(ws + 8192);       // 512 ints
    int*   node_off   = (int*)(ws + 10240);      // 513 ints
    bf16_t* wpT       = (bf16_t*)(ws + 16384);   // 64KB
    float* pbuf       = (float*)(ws + 131072);   // 256KB, fully written by k_agg_slice
    float* ybuf       = (float*)(ws + 131072 + 262144);
    size_t big0 = 1 << 20;
    size_t NB = (((size_t)N * 128 * 2) + 4095) & ~(size_t)4095;
    f16_t* ubuf = (f16_t*)(ws + big0);            // [8][N][16] f16
    f16_t* vbuf = (f16_t*)(ws + big0 + NB);       // [8][N][16] f16
    unsigned int* sorted = (unsigned int*)(ws + big0 + 2 * NB);
    f16_t* ypre  = (f16_t*)(ws + big0 + 3 * NB);
    (void)ws_size;

    // zero stats + gcnt
    (void)hipMemsetAsync(d_ws, 0, 4096, stream);

    int nb64 = (N + 63) / 64;
    k_pre_gemm<<<nb64, 256, 0, stream>>>(x, w_pre, b_pre, ypre, stats_pre, N);
    k_wprime<<<128, 256, 0, stream>>>(w_cn, wpT);
    k_uv<<<256, 256, 0, stream>>>(ypre, stats_pre, g_pre, be_pre, wpT, b_cn,
                                  ubuf, vbuf, N, nb64, 1.f / (float)N);
    k_hist<<<512, 256, 0, stream>>>(src, seg, gcnt, E);
    k_scan<<<1, 512, 0, stream>>>(gcnt, offs, cursor);
    k_nodeoff<<<(N + 255) / 256, 256, 0, stream>>>(seg, node_off, N, G);
    int nsc = (E + SC_CAP - 1) / SC_CAP;
    k_scatter<<<nsc, 512, 0, stream>>>(src, dst, seg, cursor, sorted, E, SC_CAP);
    k_agg_slice<<<8 * G, 256, 0, stream>>>(sorted, offs, node_off, ubuf, vbuf, pbuf, N);
    k_post_gemm<<<G / 16, 256, 0, stream>>>(pbuf, w_post, b_post, ybuf, stats_post);
    k_out<<<G / 4, 256, 0, stream>>>(ybuf, stats_post, g_post, be_post, w_out, b_out,
                                     (float*)d_out, 1.f / (float)G);
}

// Round 12
// 245.507 us; speedup vs baseline: 1.2260x; 1.1228x over previous
//
#include <hip/hip_runtime.h>
#include <hip/hip_bf16.h>

typedef __bf16 bf16_t;
typedef _Float16 f16_t;
typedef __attribute__((ext_vector_type(8))) __bf16 bf16x8;
typedef __attribute__((ext_vector_type(8))) _Float16 f16x8;
typedef __attribute__((ext_vector_type(4))) _Float16 f16x4;
typedef __attribute__((ext_vector_type(4))) float f32x4;

#define SC_CAP 3072   // edges per scatter block (LDS-cached)
#define MAXNR 256     // max graph node-rows staged in LDS (fallback above)

// ---------------- Phase A: GEMM y = x@w_pre + b_pre (f16) + col stats; fused wprime + hist ----------------
__global__ __launch_bounds__(256) void k_pre_gemm(const float* __restrict__ x,
        const float* __restrict__ w_pre, const float* __restrict__ b_pre,
        f16_t* __restrict__ y, float* __restrict__ stats, int N,
        const float* __restrict__ w_cn, bf16_t* __restrict__ wpT,
        const int* __restrict__ src, const int* __restrict__ seg,
        int* __restrict__ gcnt, int E) {
    __shared__ float ws[64][128];
    __shared__ float xs[64][64];
    __shared__ float red[8][2][128];
    __shared__ int lh[512];
    const int tid = threadIdx.x;
    const int row0 = blockIdx.x * 64;

    for (int i = tid; i < 64 * 128; i += 256) ws[i >> 7][i & 127] = w_pre[i];
    {
        int r = tid >> 2, q = tid & 3;
        int rg = row0 + r; if (rg >= N) rg = N - 1;
        const float4* xr = (const float4*)(x + (size_t)rg * 64 + q * 16);
        float4* dr = (float4*)(&xs[r][q * 16]);
#pragma unroll
        for (int j = 0; j < 4; ++j) dr[j] = xr[j];
    }
    __syncthreads();

    const int rg8 = tid >> 5;
    const int c0 = (tid & 31) * 4;
    float acc[8][4] = {};
    for (int k = 0; k < 64; ++k) {
        float4 wv = *(const float4*)(&ws[k][c0]);
#pragma unroll
        for (int i = 0; i < 8; ++i) {
            float xv = xs[rg8 * 8 + i][k];
            acc[i][0] += xv * wv.x;
            acc[i][1] += xv * wv.y;
            acc[i][2] += xv * wv.z;
            acc[i][3] += xv * wv.w;
        }
    }

    float bc[4];
#pragma unroll
    for (int j = 0; j < 4; ++j) bc[j] = b_pre[c0 + j];
    float s1[4] = {}, s2[4] = {};
#pragma unroll
    for (int i = 0; i < 8; ++i) {
        int row = row0 + rg8 * 8 + i;
        if (row < N) {
            f16x4 o;
#pragma unroll
            for (int j = 0; j < 4; ++j) {
                float yv = acc[i][j] + bc[j];
                o[j] = (f16_t)yv;
                s1[j] += yv; s2[j] += yv * yv;
            }
            *(f16x4*)(y + (size_t)row * 128 + c0) = o;
        }
    }
#pragma unroll
    for (int j = 0; j < 4; ++j) {
        red[rg8][0][c0 + j] = s1[j];
        red[rg8][1][c0 + j] = s2[j];
    }
    __syncthreads();
    {
        int col = tid & 127, st = tid >> 7;
        float t = 0.f;
#pragma unroll
        for (int g = 0; g < 8; ++g) t += red[g][st][col];
        atomicAdd(&stats[st * 128 + col], t);
    }

    // fused wprime: blocks 0..127 build wpT[n][k] (independent arrays, no sync needed)
    if (blockIdx.x < 128) {
        int k = blockIdx.x;
        int c = tid & 127, half = tid >> 7;
        if (half == 0)
            wpT[c * 128 + k] = (bf16_t)(w_cn[k * 128 + c] - w_cn[(128 + k) * 128 + c]);
        else
            wpT[(128 + c) * 128 + k] = (bf16_t)(w_cn[(128 + k) * 128 + c]);
    }

    // fused hist: grid-stride histogram of g = seg[src[e]]
    for (int i = tid; i < 512; i += 256) lh[i] = 0;
    __syncthreads();
    for (int e = blockIdx.x * 256 + tid; e < E; e += gridDim.x * 256)
        atomicAdd(&lh[seg[src[e]]], 1);
    __syncthreads();
    for (int i = tid; i < 512; i += 256)
        if (lh[i]) atomicAdd(&gcnt[i], lh[i]);
}

// ---------------- k_uv: BN folded from stats; [u|v] = h @ W' -> pair-major f16 [4][N][32] ----------------
__global__ __launch_bounds__(256) void k_uv(const f16_t* __restrict__ ypre,
        const float* __restrict__ stats, const float* __restrict__ g_pre,
        const float* __restrict__ be_pre, const bf16_t* __restrict__ wpT,
        const float* __restrict__ b_cn,
        f16_t* __restrict__ u, f16_t* __restrict__ v, int N, int ntiles, float invN) {
    __shared__ bf16_t at[64 * 136];
    __shared__ f16_t ot[64 * 264];
    __shared__ float a_s[128], b_s[128];

    const int tid = threadIdx.x;
    const int lane = tid & 63;
    const int wv = tid >> 6;
    const int n0 = wv * 64;
    const int l16 = lane & 15;
    const int lg = lane >> 4;

    if (tid < 128) {
        float mu = stats[tid] * invN;
        float var = stats[128 + tid] * invN - mu * mu;
        float a = g_pre[tid] * rsqrtf(var + 1e-3f);
        a_s[tid] = a;
        b_s[tid] = be_pre[tid] - mu * a;
    }

    bf16x8 bfr[4][4];
#pragma unroll
    for (int s = 0; s < 4; ++s)
#pragma unroll
        for (int c = 0; c < 4; ++c)
            bfr[s][c] = *(const bf16x8*)(wpT + (n0 + 16 * c + l16) * 128 + 32 * s + 8 * lg);

    float bias[4];
#pragma unroll
    for (int c = 0; c < 4; ++c) {
        int n = n0 + 16 * c + l16;
        bias[c] = (n < 128) ? b_cn[n] : 0.f;
    }

    const int sr = tid >> 2, sq = tid & 3;
    __syncthreads();   // a_s/b_s ready before first staging

    for (int tile = blockIdx.x; tile < ntiles; tile += gridDim.x) {
        const int row0 = tile * 64;
        {
            int rg = row0 + sr; if (rg >= N) rg = N - 1;
            const f16_t* yr = ypre + (size_t)rg * 128 + sq * 32;
            bf16_t* dr = at + sr * 136 + sq * 32;
#pragma unroll
            for (int c4 = 0; c4 < 4; ++c4) {
                f16x8 yv = *(const f16x8*)(yr + c4 * 8);
                bf16x8 hv;
#pragma unroll
                for (int j = 0; j < 8; ++j) {
                    int col = sq * 32 + c4 * 8 + j;
                    hv[j] = (bf16_t)fmaxf(a_s[col] * (float)yv[j] + b_s[col], 0.f);
                }
                *(bf16x8*)(dr + c4 * 8) = hv;
            }
        }
        __syncthreads();

        f32x4 acc[4][4];
#pragma unroll
        for (int c = 0; c < 4; ++c) {
            f32x4 ini = {bias[c], bias[c], bias[c], bias[c]};
#pragma unroll
            for (int rt = 0; rt < 4; ++rt) acc[rt][c] = ini;
        }
#pragma unroll
        for (int s = 0; s < 4; ++s) {
            bf16x8 afr[4];
#pragma unroll
            for (int rt = 0; rt < 4; ++rt)
                afr[rt] = *(const bf16x8*)(at + (rt * 16 + l16) * 136 + 32 * s + 8 * lg);
#pragma unroll
            for (int rt = 0; rt < 4; ++rt)
#pragma unroll
                for (int c = 0; c < 4; ++c)
                    acc[rt][c] = __builtin_amdgcn_mfma_f32_16x16x32_bf16(afr[rt], bfr[s][c], acc[rt][c], 0, 0, 0);
        }

#pragma unroll
        for (int rt = 0; rt < 4; ++rt)
#pragma unroll
            for (int c = 0; c < 4; ++c) {
                int n = n0 + 16 * c + l16;
#pragma unroll
                for (int reg = 0; reg < 4; ++reg) {
                    int r = rt * 16 + lg * 4 + reg;
                    ot[r * 264 + n] = (f16_t)acc[rt][c][reg];
                }
            }
        __syncthreads();

        // copy out to pair-major [4][N][32]
#pragma unroll
        for (int it = 0; it < 8; ++it) {
            int r = wv * 16 + it * 2 + (lane >> 5);
            int cc = (lane & 31) * 8;
            int rg = row0 + r;
            if (rg < N) {
                f16x8 w8 = *(const f16x8*)(ot + r * 264 + cc);
                if (cc < 128) {
                    int sp = cc >> 5, col = cc & 31;
                    *(f16x8*)(u + ((size_t)sp * N + rg) * 32 + col) = w8;
                } else {
                    int cv = cc - 128;
                    int sp = cv >> 5, col = cv & 31;
                    *(f16x8*)(v + ((size_t)sp * N + rg) * 32 + col) = w8;
                }
            }
        }
    }
}

__global__ __launch_bounds__(512) void k_scan(const int* __restrict__ gcnt,
        int* __restrict__ offs, int* __restrict__ cursor) {
    __shared__ int s[512];
    int tid = threadIdx.x;
    s[tid] = gcnt[tid];
    __syncthreads();
    for (int off = 1; off < 512; off <<= 1) {
        int v = (tid >= off) ? s[tid - off] : 0;
        __syncthreads();
        s[tid] += v;
        __syncthreads();
    }
    offs[tid + 1] = s[tid];
    int ex = tid ? s[tid - 1] : 0;
    if (tid == 0) offs[0] = 0;
    cursor[tid] = ex;
}

// ---------------- k_scatter (+ fused nodeoff): one pass, LDS-cached, u32-packed ----------------
__global__ __launch_bounds__(512) void k_scatter(const int* __restrict__ src,
        const int* __restrict__ dst, const int* __restrict__ seg,
        int* __restrict__ cursor, unsigned int* __restrict__ sorted, int E, int CH,
        int* __restrict__ node_off, int N, int G) {
    __shared__ int lh[512];
    __shared__ int lbase[512];
    __shared__ unsigned int pcache[SC_CAP];
    __shared__ unsigned short gcache[SC_CAP];
    const int tid = threadIdx.x;

    // fused nodeoff: node_off[g] = first node row of graph g (seg sorted)
    {
        int i = blockIdx.x * 512 + tid;
        if (i < N) {
            int s = seg[i];
            int prev = (i == 0) ? -1 : seg[i - 1];
            for (int g2 = prev + 1; g2 <= s; ++g2) node_off[g2] = i;
            if (i == N - 1)
                for (int g2 = s + 1; g2 <= G; ++g2) node_off[g2] = N;
        }
    }

    const int e0 = blockIdx.x * CH;
    const int e1 = min(E, e0 + CH);
    lh[tid] = 0;
    __syncthreads();
    for (int e = e0 + tid; e < e1; e += 512) {
        int si = src[e], di = dst[e];
        int g = seg[si];
        pcache[e - e0] = ((unsigned)si << 16) | (unsigned)di;
        gcache[e - e0] = (unsigned short)g;
        atomicAdd(&lh[g], 1);
    }
    __syncthreads();
    {
        int c = lh[tid];
        lbase[tid] = c ? atomicAdd(&cursor[tid], c) : 0;
        lh[tid] = 0;
    }
    __syncthreads();
    for (int e = e0 + tid; e < e1; e += 512) {
        int g = gcache[e - e0];
        int k = atomicAdd(&lh[g], 1);
        sorted[lbase[g] + k] = pcache[e - e0];
    }
}

// ---------------- k_agg_pair: block (g, sp) owns 32-col pair-slice sp of graph g ----------------
// sp = (bid&7)>>1 -> pair sp pinned to XCDs {2sp,2sp+1}; v-pair (3.2MB) L2-resident.
// v-row slice = 64B read by 4 consecutive lanes -> fully coalesced segments.
// u staged in LDS (stride 40 f16 = 80B -> b128 start slots spread over all 8 4-dw slots).
__global__ __launch_bounds__(256) void k_agg_pair(const unsigned int* __restrict__ sorted,
        const int* __restrict__ offs, const int* __restrict__ node_off,
        const f16_t* __restrict__ u, const f16_t* __restrict__ v,
        float* __restrict__ p, int N) {
    const int bid = blockIdx.x;
    const int sp = (bid & 7) >> 1;
    const int g = (bid >> 3) * 2 + (bid & 1);
    const int s0 = offs[g], s1 = offs[g + 1];
    const int r0 = node_off[g];
    const int nr = node_off[g + 1] - r0;
    const int tid = threadIdx.x;
    const int lane = tid & 63;
    const int wv = tid >> 6;
    const int eidx = lane >> 2;        // 16 edges per wave-chunk
    const int c0 = (lane & 3) * 8;     // 8 cols per lane (4 lanes cover 32 cols = 64B)
    const f16_t* ug = u + (size_t)sp * N * 32;
    const f16_t* vg = v + (size_t)sp * N * 32;
    const f16x8 zero = {};
    float acc[8] = {};

    __shared__ f16_t ulds[MAXNR * 40];   // row stride 40 f16 = 80B
    __shared__ float red[4][4][8];

    if (nr <= MAXNR) {
        // stage u rows [r0, r0+nr) x 32 cols: contiguous global -> LDS, coalesced
        for (int i = tid; i < nr * 4; i += 256) {
            int row = i >> 2, q = i & 3;
            *(f16x8*)(ulds + row * 40 + q * 8) =
                *(const f16x8*)(ug + (size_t)(r0 + row) * 32 + q * 8);
        }
        __syncthreads();

        int base = s0 + wv * 16;
        for (; base + 80 <= s1; base += 128) {   // 2 streams, unguarded
            unsigned pA = sorted[base + eidx];
            unsigned pB = sorted[base + 64 + eidx];
            f16x8 vA = *(const f16x8*)(vg + (size_t)(pA & 0xffffu) * 32 + c0);
            f16x8 vB = *(const f16x8*)(vg + (size_t)(pB & 0xffffu) * 32 + c0);
            f16x8 uA = *(const f16x8*)(ulds + ((int)(pA >> 16) - r0) * 40 + c0);
            f16x8 uB = *(const f16x8*)(ulds + ((int)(pB >> 16) - r0) * 40 + c0);
            f16x8 rA = __builtin_elementwise_max(uA + vA, zero);
            f16x8 rB = __builtin_elementwise_max(uB + vB, zero);
#pragma unroll
            for (int j = 0; j < 8; ++j) acc[j] += (float)rA[j];
#pragma unroll
            for (int j = 0; j < 8; ++j) acc[j] += (float)rB[j];
        }
        for (; base < s1; base += 64) {          // guarded tail
            int e = base + eidx;
            if (e < s1) {
                unsigned pk = sorted[e];
                f16x8 vv = *(const f16x8*)(vg + (size_t)(pk & 0xffffu) * 32 + c0);
                f16x8 uu = *(const f16x8*)(ulds + ((int)(pk >> 16) - r0) * 40 + c0);
                f16x8 r = __builtin_elementwise_max(uu + vv, zero);
#pragma unroll
                for (int j = 0; j < 8; ++j) acc[j] += (float)r[j];
            }
        }
    } else {
        // fallback: global u gather (also 64B-coalesced), 2 streams
        int base = s0 + wv * 16;
        for (; base + 80 <= s1; base += 128) {
            unsigned pA = sorted[base + eidx];
            unsigned pB = sorted[base + 64 + eidx];
            f16x8 uA = *(const f16x8*)(ug + (size_t)(pA >> 16) * 32 + c0);
            f16x8 vA = *(const f16x8*)(vg + (size_t)(pA & 0xffffu) * 32 + c0);
            f16x8 uB = *(const f16x8*)(ug + (size_t)(pB >> 16) * 32 + c0);
            f16x8 vB = *(const f16x8*)(vg + (size_t)(pB & 0xffffu) * 32 + c0);
            f16x8 rA = __builtin_elementwise_max(uA + vA, zero);
            f16x8 rB = __builtin_elementwise_max(uB + vB, zero);
#pragma unroll
            for (int j = 0; j < 8; ++j) acc[j] += (float)rA[j];
#pragma unroll
            for (int j = 0; j < 8; ++j) acc[j] += (float)rB[j];
        }
        for (; base < s1; base += 64) {
            int e = base + eidx;
            if (e < s1) {
                unsigned pk = sorted[e];
                f16x8 uu = *(const f16x8*)(ug + (size_t)(pk >> 16) * 32 + c0);
                f16x8 vv = *(const f16x8*)(vg + (size_t)(pk & 0xffffu) * 32 + c0);
                f16x8 r = __builtin_elementwise_max(uu + vv, zero);
#pragma unroll
                for (int j = 0; j < 8; ++j) acc[j] += (float)r[j];
            }
        }
    }

    // reduce across the 16 edge-groups (lane bits 2..5)
#pragma unroll
    for (int j = 0; j < 8; ++j) {
        acc[j] += __shfl_xor(acc[j], 4, 64);
        acc[j] += __shfl_xor(acc[j], 8, 64);
        acc[j] += __shfl_xor(acc[j], 16, 64);
        acc[j] += __shfl_xor(acc[j], 32, 64);
    }
    if (lane < 4) {
#pragma unroll
        for (int j = 0; j < 8; ++j) red[wv][lane][j] = acc[j];
    }
    __syncthreads();
    if (tid < 32) {
        int cs = tid >> 3, j = tid & 7;
        float sum = red[0][cs][j] + red[1][cs][j] + red[2][cs][j] + red[3][cs][j];
        p[g * 128 + sp * 32 + cs * 8 + j] = sum;   // exclusive owner: plain store
    }
}

// ---------------- Phase C: post MLP + BN + head ----------------
__global__ __launch_bounds__(256) void k_post_gemm(const float* __restrict__ p,
        const float* __restrict__ w_post, const float* __restrict__ b_post,
        float* __restrict__ y, float* __restrict__ stats) {
    int tid = threadIdx.x;
    int row0 = blockIdx.x * 16;
    int col = tid & 127, rg = tid >> 7;
    float acc[8] = {};
    for (int k = 0; k < 128; ++k) {
        float wv = w_post[k * 128 + col];
#pragma unroll
        for (int i = 0; i < 8; ++i) acc[i] += p[(row0 + rg * 8 + i) * 128 + k] * wv;
    }
    float b = b_post[col], s1 = 0.f, s2 = 0.f;
#pragma unroll
    for (int i = 0; i < 8; ++i) {
        float yv = acc[i] + b;
        y[(row0 + rg * 8 + i) * 128 + col] = yv;
        s1 += yv; s2 += yv * yv;
    }
    atomicAdd(&stats[col], s1);
    atomicAdd(&stats[128 + col], s2);
}

__global__ __launch_bounds__(256) void k_out(const float* __restrict__ y,
        const float* __restrict__ stats, const float* __restrict__ g_post,
        const float* __restrict__ be_post, const float* __restrict__ w_out,
        const float* __restrict__ b_out, float* __restrict__ out, float invG) {
    __shared__ float a_s[128], b_s[128];
    int tid = threadIdx.x;
    if (tid < 128) {
        float mu = stats[tid] * invG;
        float var = stats[128 + tid] * invG - mu * mu;
        float a = g_post[tid] * rsqrtf(var + 1e-3f);
        a_s[tid] = a;
        b_s[tid] = be_post[tid] - mu * a;
    }
    __syncthreads();
    int lane = tid & 63;
    int wv = tid >> 6;
    int row = blockIdx.x * 4 + wv;
    int c0 = lane * 2;
    float v = 0.f;
#pragma unroll
    for (int j = 0; j < 2; ++j) {
        int c = c0 + j;
        float t = fmaxf(a_s[c] * y[row * 128 + c] + b_s[c], 0.f);
        v += t * w_out[c];
    }
#pragma unroll
    for (int m = 32; m >= 1; m >>= 1) v += __shfl_xor(v, m, 64);
    if (lane == 0) out[row] = 1.f / (1.f + expf(-(v + b_out[0])));
}

extern "C" void kernel_launch(void* const* d_in, const int* in_sizes, int n_in,
                              void* d_out, int out_size, void* d_ws, size_t ws_size,
                              hipStream_t stream) {
    const float* x      = (const float*)d_in[0];
    const int*   src    = (const int*)d_in[1];
    const int*   dst    = (const int*)d_in[2];
    const int*   seg    = (const int*)d_in[3];
    const float* w_pre  = (const float*)d_in[4];
    const float* b_pre  = (const float*)d_in[5];
    const float* g_pre  = (const float*)d_in[6];
    const float* be_pre = (const float*)d_in[7];
    const float* w_cn   = (const float*)d_in[8];
    const float* b_cn   = (const float*)d_in[9];
    const float* w_post = (const float*)d_in[10];
    const float* b_post = (const float*)d_in[11];
    const float* g_post = (const float*)d_in[12];
    const float* be_post= (const float*)d_in[13];
    const float* w_out  = (const float*)d_in[14];
    const float* b_out  = (const float*)d_in[15];
    const int E = in_sizes[1];
    const int N = in_sizes[3];
    const int G = out_size;

    char* ws = (char*)d_ws;
    float* stats_pre  = (float*)(ws + 0);        // zeroed each call
    float* stats_post = (float*)(ws + 1024);     // zeroed each call
    int*   gcnt       = (int*)(ws + 2048);       // zeroed each call
    int*   offs       = (int*)(ws + 4096);       // 513 ints
    int*   cursor     = (int*)(ws + 8192);       // 512 ints
    int*   node_off   = (int*)(ws + 10240);      // 513 ints
    bf16_t* wpT       = (bf16_t*)(ws + 16384);   // 64KB
    float* pbuf       = (float*)(ws + 131072);   // 256KB, fully written by k_agg_pair
    float* ybuf       = (float*)(ws + 131072 + 262144);
    size_t big0 = 1 << 20;
    size_t NB = (((size_t)N * 128 * 2) + 4095) & ~(size_t)4095;
    f16_t* ubuf = (f16_t*)(ws + big0);            // [4][N][32] f16
    f16_t* vbuf = (f16_t*)(ws + big0 + NB);       // [4][N][32] f16
    unsigned int* sorted = (unsigned int*)(ws + big0 + 2 * NB);
    f16_t* ypre  = (f16_t*)(ws + big0 + 3 * NB);
    (void)ws_size;

    (void)hipMemsetAsync(d_ws, 0, 4096, stream);

    int nb64 = (N + 63) / 64;
    k_pre_gemm<<<nb64, 256, 0, stream>>>(x, w_pre, b_pre, ypre, stats_pre, N,
                                         w_cn, wpT, src, seg, gcnt, E);
    k_uv<<<256, 256, 0, stream>>>(ypre, stats_pre, g_pre, be_pre, wpT, b_cn,
                                  ubuf, vbuf, N, nb64, 1.f / (float)N);
    k_scan<<<1, 512, 0, stream>>>(gcnt, offs, cursor);
    int nsc = (E + SC_CAP - 1) / SC_CAP;
    k_scatter<<<nsc, 512, 0, stream>>>(src, dst, seg, cursor, sorted, E, SC_CAP,
                                       node_off, N, G);
    k_agg_pair<<<8 * (G / 2), 256, 0, stream>>>(sorted, offs, node_off, ubuf, vbuf, pbuf, N);
    k_post_gemm<<<G / 16, 256, 0, stream>>>(pbuf, w_post, b_post, ybuf, stats_post);
    k_out<<<G / 4, 256, 0, stream>>>(ybuf, stats_post, g_post, be_post, w_out, b_out,
                                     (float*)d_out, 1.f / (float)G);
}

// Round 13
// 241.290 us; speedup vs baseline: 1.2474x; 1.0175x over previous
//
#include <hip/hip_runtime.h>
#include <hip/hip_bf16.h>

typedef __bf16 bf16_t;
typedef _Float16 f16_t;
typedef __attribute__((ext_vector_type(8))) __bf16 bf16x8;
typedef __attribute__((ext_vector_type(8))) _Float16 f16x8;
typedef __attribute__((ext_vector_type(4))) _Float16 f16x4;
typedef __attribute__((ext_vector_type(4))) float f32x4;

#define SC_CAP 3072   // edges per scatter block (LDS-cached)
#define MAXNR 160     // max graph node-rows staged in LDS (fallback above)

// ---------------- Phase A: GEMM y = x@w_pre + b_pre (f16) + col stats; fused wprime + hist ----------------
__global__ __launch_bounds__(256) void k_pre_gemm(const float* __restrict__ x,
        const float* __restrict__ w_pre, const float* __restrict__ b_pre,
        f16_t* __restrict__ y, float* __restrict__ stats, int N,
        const float* __restrict__ w_cn, bf16_t* __restrict__ wpT,
        const int* __restrict__ src, const int* __restrict__ seg,
        int* __restrict__ gcnt, int E) {
    __shared__ float ws[64][128];
    __shared__ float xs[64][64];
    __shared__ float red[8][2][128];
    __shared__ int lh[512];
    const int tid = threadIdx.x;
    const int row0 = blockIdx.x * 64;

    for (int i = tid; i < 64 * 128; i += 256) ws[i >> 7][i & 127] = w_pre[i];
    {
        int r = tid >> 2, q = tid & 3;
        int rg = row0 + r; if (rg >= N) rg = N - 1;
        const float4* xr = (const float4*)(x + (size_t)rg * 64 + q * 16);
        float4* dr = (float4*)(&xs[r][q * 16]);
#pragma unroll
        for (int j = 0; j < 4; ++j) dr[j] = xr[j];
    }
    __syncthreads();

    const int rg8 = tid >> 5;
    const int c0 = (tid & 31) * 4;
    float acc[8][4] = {};
    for (int k = 0; k < 64; ++k) {
        float4 wv = *(const float4*)(&ws[k][c0]);
#pragma unroll
        for (int i = 0; i < 8; ++i) {
            float xv = xs[rg8 * 8 + i][k];
            acc[i][0] += xv * wv.x;
            acc[i][1] += xv * wv.y;
            acc[i][2] += xv * wv.z;
            acc[i][3] += xv * wv.w;
        }
    }

    float bc[4];
#pragma unroll
    for (int j = 0; j < 4; ++j) bc[j] = b_pre[c0 + j];
    float s1[4] = {}, s2[4] = {};
#pragma unroll
    for (int i = 0; i < 8; ++i) {
        int row = row0 + rg8 * 8 + i;
        if (row < N) {
            f16x4 o;
#pragma unroll
            for (int j = 0; j < 4; ++j) {
                float yv = acc[i][j] + bc[j];
                o[j] = (f16_t)yv;
                s1[j] += yv; s2[j] += yv * yv;
            }
            *(f16x4*)(y + (size_t)row * 128 + c0) = o;
        }
    }
#pragma unroll
    for (int j = 0; j < 4; ++j) {
        red[rg8][0][c0 + j] = s1[j];
        red[rg8][1][c0 + j] = s2[j];
    }
    __syncthreads();
    {
        int col = tid & 127, st = tid >> 7;
        float t = 0.f;
#pragma unroll
        for (int g = 0; g < 8; ++g) t += red[g][st][col];
        atomicAdd(&stats[st * 128 + col], t);
    }

    // fused wprime: blocks 0..127 build wpT[n][k]
    if (blockIdx.x < 128) {
        int k = blockIdx.x;
        int c = tid & 127, half = tid >> 7;
        if (half == 0)
            wpT[c * 128 + k] = (bf16_t)(w_cn[k * 128 + c] - w_cn[(128 + k) * 128 + c]);
        else
            wpT[(128 + c) * 128 + k] = (bf16_t)(w_cn[(128 + k) * 128 + c]);
    }

    // fused hist: grid-stride histogram of g = seg[src[e]]
    for (int i = tid; i < 512; i += 256) lh[i] = 0;
    __syncthreads();
    for (int e = blockIdx.x * 256 + tid; e < E; e += gridDim.x * 256)
        atomicAdd(&lh[seg[src[e]]], 1);
    __syncthreads();
    for (int i = tid; i < 512; i += 256)
        if (lh[i]) atomicAdd(&gcnt[i], lh[i]);
}

// ---------------- k_uv: BN folded from stats; [u|v] = h @ W' -> pair-major f16 [4][N][32] ----------------
__global__ __launch_bounds__(256) void k_uv(const f16_t* __restrict__ ypre,
        const float* __restrict__ stats, const float* __restrict__ g_pre,
        const float* __restrict__ be_pre, const bf16_t* __restrict__ wpT,
        const float* __restrict__ b_cn,
        f16_t* __restrict__ u, f16_t* __restrict__ v, int N, int ntiles, float invN) {
    __shared__ bf16_t at[64 * 136];
    __shared__ f16_t ot[64 * 264];
    __shared__ float a_s[128], b_s[128];

    const int tid = threadIdx.x;
    const int lane = tid & 63;
    const int wv = tid >> 6;
    const int n0 = wv * 64;
    const int l16 = lane & 15;
    const int lg = lane >> 4;

    if (tid < 128) {
        float mu = stats[tid] * invN;
        float var = stats[128 + tid] * invN - mu * mu;
        float a = g_pre[tid] * rsqrtf(var + 1e-3f);
        a_s[tid] = a;
        b_s[tid] = be_pre[tid] - mu * a;
    }

    bf16x8 bfr[4][4];
#pragma unroll
    for (int s = 0; s < 4; ++s)
#pragma unroll
        for (int c = 0; c < 4; ++c)
            bfr[s][c] = *(const bf16x8*)(wpT + (n0 + 16 * c + l16) * 128 + 32 * s + 8 * lg);

    float bias[4];
#pragma unroll
    for (int c = 0; c < 4; ++c) {
        int n = n0 + 16 * c + l16;
        bias[c] = (n < 128) ? b_cn[n] : 0.f;
    }

    const int sr = tid >> 2, sq = tid & 3;
    __syncthreads();   // a_s/b_s ready before first staging

    for (int tile = blockIdx.x; tile < ntiles; tile += gridDim.x) {
        const int row0 = tile * 64;
        {
            int rg = row0 + sr; if (rg >= N) rg = N - 1;
            const f16_t* yr = ypre + (size_t)rg * 128 + sq * 32;
            bf16_t* dr = at + sr * 136 + sq * 32;
#pragma unroll
            for (int c4 = 0; c4 < 4; ++c4) {
                f16x8 yv = *(const f16x8*)(yr + c4 * 8);
                bf16x8 hv;
#pragma unroll
                for (int j = 0; j < 8; ++j) {
                    int col = sq * 32 + c4 * 8 + j;
                    hv[j] = (bf16_t)fmaxf(a_s[col] * (float)yv[j] + b_s[col], 0.f);
                }
                *(bf16x8*)(dr + c4 * 8) = hv;
            }
        }
        __syncthreads();

        f32x4 acc[4][4];
#pragma unroll
        for (int c = 0; c < 4; ++c) {
            f32x4 ini = {bias[c], bias[c], bias[c], bias[c]};
#pragma unroll
            for (int rt = 0; rt < 4; ++rt) acc[rt][c] = ini;
        }
#pragma unroll
        for (int s = 0; s < 4; ++s) {
            bf16x8 afr[4];
#pragma unroll
            for (int rt = 0; rt < 4; ++rt)
                afr[rt] = *(const bf16x8*)(at + (rt * 16 + l16) * 136 + 32 * s + 8 * lg);
#pragma unroll
            for (int rt = 0; rt < 4; ++rt)
#pragma unroll
                for (int c = 0; c < 4; ++c)
                    acc[rt][c] = __builtin_amdgcn_mfma_f32_16x16x32_bf16(afr[rt], bfr[s][c], acc[rt][c], 0, 0, 0);
        }

#pragma unroll
        for (int rt = 0; rt < 4; ++rt)
#pragma unroll
            for (int c = 0; c < 4; ++c) {
                int n = n0 + 16 * c + l16;
#pragma unroll
                for (int reg = 0; reg < 4; ++reg) {
                    int r = rt * 16 + lg * 4 + reg;
                    ot[r * 264 + n] = (f16_t)acc[rt][c][reg];
                }
            }
        __syncthreads();

        // copy out to pair-major [4][N][32]
#pragma unroll
        for (int it = 0; it < 8; ++it) {
            int r = wv * 16 + it * 2 + (lane >> 5);
            int cc = (lane & 31) * 8;
            int rg = row0 + r;
            if (rg < N) {
                f16x8 w8 = *(const f16x8*)(ot + r * 264 + cc);
                if (cc < 128) {
                    int sp = cc >> 5, col = cc & 31;
                    *(f16x8*)(u + ((size_t)sp * N + rg) * 32 + col) = w8;
                } else {
                    int cv = cc - 128;
                    int sp = cv >> 5, col = cv & 31;
                    *(f16x8*)(v + ((size_t)sp * N + rg) * 32 + col) = w8;
                }
            }
        }
    }
}

// ---------------- k_scatter (+ fused scan + nodeoff): one pass, LDS-cached, u32-packed ----------------
__global__ __launch_bounds__(512) void k_scatter(const int* __restrict__ src,
        const int* __restrict__ dst, const int* __restrict__ seg,
        int* __restrict__ cursor, unsigned int* __restrict__ sorted, int E, int CH,
        int* __restrict__ node_off, int N, int G,
        const int* __restrict__ gcnt, int* __restrict__ offs) {
    __shared__ int pref[512];
    __shared__ int lh[512];
    __shared__ int lbase[512];
    __shared__ unsigned int pcache[SC_CAP];
    __shared__ unsigned short gcache[SC_CAP];
    const int tid = threadIdx.x;

    // fused scan of gcnt (every block computes it; block 0 publishes offs)
    int gc = gcnt[tid];
    pref[tid] = gc;
    __syncthreads();
    for (int off = 1; off < 512; off <<= 1) {
        int vv = (tid >= off) ? pref[tid - off] : 0;
        __syncthreads();
        pref[tid] += vv;
        __syncthreads();
    }
    if (blockIdx.x == 0) {
        offs[tid + 1] = pref[tid];
        if (tid == 0) offs[0] = 0;
    }
    const int excl = pref[tid] - gc;

    // fused nodeoff: node_off[g] = first node row of graph g (seg sorted)
    {
        int i = blockIdx.x * 512 + tid;
        if (i < N) {
            int s = seg[i];
            int prev = (i == 0) ? -1 : seg[i - 1];
            for (int g2 = prev + 1; g2 <= s; ++g2) node_off[g2] = i;
            if (i == N - 1)
                for (int g2 = s + 1; g2 <= G; ++g2) node_off[g2] = N;
        }
    }

    const int e0 = blockIdx.x * CH;
    const int e1 = min(E, e0 + CH);
    lh[tid] = 0;
    __syncthreads();
    for (int e = e0 + tid; e < e1; e += 512) {
        int si = src[e], di = dst[e];
        int g = seg[si];
        pcache[e - e0] = ((unsigned)si << 16) | (unsigned)di;
        gcache[e - e0] = (unsigned short)g;
        atomicAdd(&lh[g], 1);
    }
    __syncthreads();
    {
        int c = lh[tid];
        lbase[tid] = c ? (excl + atomicAdd(&cursor[tid], c)) : 0;
        lh[tid] = 0;
    }
    __syncthreads();
    for (int e = e0 + tid; e < e1; e += 512) {
        int g = gcache[e - e0];
        int k = atomicAdd(&lh[g], 1);
        sorted[lbase[g] + k] = pcache[e - e0];
    }
}

// ---------------- k_agg_pair: block (g, sp, span); 32-col pair-slice, 2 edge-spans ----------------
// sp = (bid&7)>>1 -> pair sp pinned to XCDs {2sp,2sp+1}; v-pair (3.2MB) L2-resident.
// v-row slice = 64B read by 4 consecutive lanes -> fully coalesced segments.
// u staged in LDS (stride 40 f16 = 80B). Epilogue: 32 atomicAdds into pre-zeroed p.
__global__ __launch_bounds__(256) void k_agg_pair(const unsigned int* __restrict__ sorted,
        const int* __restrict__ offs, const int* __restrict__ node_off,
        const f16_t* __restrict__ u, const f16_t* __restrict__ v,
        float* __restrict__ p, int N) {
    const int bid = blockIdx.x;
    const int sp = (bid & 7) >> 1;
    const int span = (bid >> 3) & 1;
    const int g = (bid >> 4) * 2 + (bid & 1);
    const int s0 = offs[g], s1 = offs[g + 1];
    const int r0 = node_off[g];
    const int nr = node_off[g + 1] - r0;
    const int tid = threadIdx.x;
    const int lane = tid & 63;
    const int wv = tid >> 6;
    const int eidx = lane >> 2;        // 16 edges per wave-chunk
    const int c0 = (lane & 3) * 8;     // 8 cols per lane (4 lanes cover 32 cols = 64B)
    const f16_t* ug = u + (size_t)sp * N * 32;
    const f16_t* vg = v + (size_t)sp * N * 32;
    const f16x8 zero = {};
    float acc[8] = {};

    __shared__ f16_t ulds[MAXNR * 40];   // row stride 40 f16 = 80B
    __shared__ float red[4][4][8];

    if (nr <= MAXNR) {
        // stage u rows [r0, r0+nr) x 32 cols: contiguous global -> LDS, coalesced
        for (int i = tid; i < nr * 4; i += 256) {
            int row = i >> 2, q = i & 3;
            *(f16x8*)(ulds + row * 40 + q * 8) =
                *(const f16x8*)(ug + (size_t)(r0 + row) * 32 + q * 8);
        }
        __syncthreads();

        int base = s0 + (span * 4 + wv) * 16;
        for (; base + 144 <= s1; base += 256) {   // 2 streams, unguarded
            unsigned pA = sorted[base + eidx];
            unsigned pB = sorted[base + 128 + eidx];
            f16x8 vA = *(const f16x8*)(vg + (size_t)(pA & 0xffffu) * 32 + c0);
            f16x8 vB = *(const f16x8*)(vg + (size_t)(pB & 0xffffu) * 32 + c0);
            f16x8 uA = *(const f16x8*)(ulds + ((int)(pA >> 16) - r0) * 40 + c0);
            f16x8 uB = *(const f16x8*)(ulds + ((int)(pB >> 16) - r0) * 40 + c0);
            f16x8 rA = __builtin_elementwise_max(uA + vA, zero);
            f16x8 rB = __builtin_elementwise_max(uB + vB, zero);
#pragma unroll
            for (int j = 0; j < 8; ++j) acc[j] += (float)rA[j];
#pragma unroll
            for (int j = 0; j < 8; ++j) acc[j] += (float)rB[j];
        }
        for (; base < s1; base += 128) {          // guarded tail
            int e = base + eidx;
            if (e < s1) {
                unsigned pk = sorted[e];
                f16x8 vv = *(const f16x8*)(vg + (size_t)(pk & 0xffffu) * 32 + c0);
                f16x8 uu = *(const f16x8*)(ulds + ((int)(pk >> 16) - r0) * 40 + c0);
                f16x8 r = __builtin_elementwise_max(uu + vv, zero);
#pragma unroll
                for (int j = 0; j < 8; ++j) acc[j] += (float)r[j];
            }
        }
    } else {
        // fallback: global u gather (also 64B-coalesced), 2 streams
        int base = s0 + (span * 4 + wv) * 16;
        for (; base + 144 <= s1; base += 256) {
            unsigned pA = sorted[base + eidx];
            unsigned pB = sorted[base + 128 + eidx];
            f16x8 uA = *(const f16x8*)(ug + (size_t)(pA >> 16) * 32 + c0);
            f16x8 vA = *(const f16x8*)(vg + (size_t)(pA & 0xffffu) * 32 + c0);
            f16x8 uB = *(const f16x8*)(ug + (size_t)(pB >> 16) * 32 + c0);
            f16x8 vB = *(const f16x8*)(vg + (size_t)(pB & 0xffffu) * 32 + c0);
            f16x8 rA = __builtin_elementwise_max(uA + vA, zero);
            f16x8 rB = __builtin_elementwise_max(uB + vB, zero);
#pragma unroll
            for (int j = 0; j < 8; ++j) acc[j] += (float)rA[j];
#pragma unroll
            for (int j = 0; j < 8; ++j) acc[j] += (float)rB[j];
        }
        for (; base < s1; base += 128) {
            int e = base + eidx;
            if (e < s1) {
                unsigned pk = sorted[e];
                f16x8 uu = *(const f16x8*)(ug + (size_t)(pk >> 16) * 32 + c0);
                f16x8 vv = *(const f16x8*)(vg + (size_t)(pk & 0xffffu) * 32 + c0);
                f16x8 r = __builtin_elementwise_max(uu + vv, zero);
#pragma unroll
                for (int j = 0; j < 8; ++j) acc[j] += (float)r[j];
            }
        }
    }

    // reduce across the 16 edge-groups (lane bits 2..5)
#pragma unroll
    for (int j = 0; j < 8; ++j) {
        acc[j] += __shfl_xor(acc[j], 4, 64);
        acc[j] += __shfl_xor(acc[j], 8, 64);
        acc[j] += __shfl_xor(acc[j], 16, 64);
        acc[j] += __shfl_xor(acc[j], 32, 64);
    }
    if (lane < 4) {
#pragma unroll
        for (int j = 0; j < 8; ++j) red[wv][lane][j] = acc[j];
    }
    __syncthreads();
    if (tid < 32) {
        int cs = tid >> 3, j = tid & 7;
        float sum = red[0][cs][j] + red[1][cs][j] + red[2][cs][j] + red[3][cs][j];
        atomicAdd(&p[g * 128 + sp * 32 + cs * 8 + j], sum);
    }
}

// ---------------- Phase C: post MLP + BN + head ----------------
__global__ __launch_bounds__(256) void k_post_gemm(const float* __restrict__ p,
        const float* __restrict__ w_post, const float* __restrict__ b_post,
        float* __restrict__ y, float* __restrict__ stats) {
    int tid = threadIdx.x;
    int row0 = blockIdx.x * 16;
    int col = tid & 127, rg = tid >> 7;
    float acc[8] = {};
    for (int k = 0; k < 128; ++k) {
        float wv = w_post[k * 128 + col];
#pragma unroll
        for (int i = 0; i < 8; ++i) acc[i] += p[(row0 + rg * 8 + i) * 128 + k] * wv;
    }
    float b = b_post[col], s1 = 0.f, s2 = 0.f;
#pragma unroll
    for (int i = 0; i < 8; ++i) {
        float yv = acc[i] + b;
        y[(row0 + rg * 8 + i) * 128 + col] = yv;
        s1 += yv; s2 += yv * yv;
    }
    atomicAdd(&stats[col], s1);
    atomicAdd(&stats[128 + col], s2);
}

__global__ __launch_bounds__(256) void k_out(const float* __restrict__ y,
        const float* __restrict__ stats, const float* __restrict__ g_post,
        const float* __restrict__ be_post, const float* __restrict__ w_out,
        const float* __restrict__ b_out, float* __restrict__ out, float invG) {
    __shared__ float a_s[128], b_s[128];
    int tid = threadIdx.x;
    if (tid < 128) {
        float mu = stats[tid] * invG;
        float var = stats[128 + tid] * invG - mu * mu;
        float a = g_post[tid] * rsqrtf(var + 1e-3f);
        a_s[tid] = a;
        b_s[tid] = be_post[tid] - mu * a;
    }
    __syncthreads();
    int lane = tid & 63;
    int wv = tid >> 6;
    int row = blockIdx.x * 4 + wv;
    int c0 = lane * 2;
    float v = 0.f;
#pragma unroll
    for (int j = 0; j < 2; ++j) {
        int c = c0 + j;
        float t = fmaxf(a_s[c] * y[row * 128 + c] + b_s[c], 0.f);
        v += t * w_out[c];
    }
#pragma unroll
    for (int m = 32; m >= 1; m >>= 1) v += __shfl_xor(v, m, 64);
    if (lane == 0) out[row] = 1.f / (1.f + expf(-(v + b_out[0])));
}

extern "C" void kernel_launch(void* const* d_in, const int* in_sizes, int n_in,
                              void* d_out, int out_size, void* d_ws, size_t ws_size,
                              hipStream_t stream) {
    const float* x      = (const float*)d_in[0];
    const int*   src    = (const int*)d_in[1];
    const int*   dst    = (const int*)d_in[2];
    const int*   seg    = (const int*)d_in[3];
    const float* w_pre  = (const float*)d_in[4];
    const float* b_pre  = (const float*)d_in[5];
    const float* g_pre  = (const float*)d_in[6];
    const float* be_pre = (const float*)d_in[7];
    const float* w_cn   = (const float*)d_in[8];
    const float* b_cn   = (const float*)d_in[9];
    const float* w_post = (const float*)d_in[10];
    const float* b_post = (const float*)d_in[11];
    const float* g_post = (const float*)d_in[12];
    const float* be_post= (const float*)d_in[13];
    const float* w_out  = (const float*)d_in[14];
    const float* b_out  = (const float*)d_in[15];
    const int E = in_sizes[1];
    const int N = in_sizes[3];
    const int G = out_size;

    char* ws = (char*)d_ws;
    float* stats_pre  = (float*)(ws + 0);        // zeroed each call
    float* stats_post = (float*)(ws + 1024);     // zeroed each call
    int*   gcnt       = (int*)(ws + 2048);       // zeroed each call
    int*   offs       = (int*)(ws + 4096);       // 513 ints (written by scatter blk 0)
    int*   cursor     = (int*)(ws + 8192);       // 512 ints, zeroed each call
    int*   node_off   = (int*)(ws + 10240);      // 513 ints
    bf16_t* wpT       = (bf16_t*)(ws + 16384);   // 64KB
    float* pbuf       = (float*)(ws + 131072);   // 256KB, zeroed (atomic accum)
    float* ybuf       = (float*)(ws + 131072 + 262144);
    size_t big0 = 1 << 20;
    size_t NB = (((size_t)N * 128 * 2) + 4095) & ~(size_t)4095;
    f16_t* ubuf = (f16_t*)(ws + big0);            // [4][N][32] f16
    f16_t* vbuf = (f16_t*)(ws + big0 + NB);       // [4][N][32] f16
    unsigned int* sorted = (unsigned int*)(ws + big0 + 2 * NB);
    f16_t* ypre  = (f16_t*)(ws + big0 + 3 * NB);
    (void)ws_size;

    // zero stats/gcnt/cursor (and offs region, rewritten later) + pbuf
    (void)hipMemsetAsync(ws, 0, 10240, stream);
    (void)hipMemsetAsync(ws + 131072, 0, 262144, stream);

    int nb64 = (N + 63) / 64;
    k_pre_gemm<<<nb64, 256, 0, stream>>>(x, w_pre, b_pre, ypre, stats_pre, N,
                                         w_cn, wpT, src, seg, gcnt, E);
    k_uv<<<nb64, 256, 0, stream>>>(ypre, stats_pre, g_pre, be_pre, wpT, b_cn,
                                   ubuf, vbuf, N, nb64, 1.f / (float)N);
    int nsc = (E + SC_CAP - 1) / SC_CAP;
    k_scatter<<<nsc, 512, 0, stream>>>(src, dst, seg, cursor, sorted, E, SC_CAP,
                                       node_off, N, G, gcnt, offs);
    k_agg_pair<<<16 * (G / 2), 256, 0, stream>>>(sorted, offs, node_off, ubuf, vbuf, pbuf, N);
    k_post_gemm<<<G / 16, 256, 0, stream>>>(pbuf, w_post, b_post, ybuf, stats_post);
    k_out<<<G / 4, 256, 0, stream>>>(ybuf, stats_post, g_post, be_post, w_out, b_out,
                                     (float*)d_out, 1.f / (float)G);
}

// Round 14
// 236.218 us; speedup vs baseline: 1.2742x; 1.0215x over previous
//
#include <hip/hip_runtime.h>
#include <hip/hip_bf16.h>

typedef __bf16 bf16_t;
typedef _Float16 f16_t;
typedef __attribute__((ext_vector_type(8))) __bf16 bf16x8;
typedef __attribute__((ext_vector_type(8))) _Float16 f16x8;
typedef __attribute__((ext_vector_type(4))) _Float16 f16x4;
typedef __attribute__((ext_vector_type(4))) float f32x4;

#define SC_CAP 3072   // edges per scatter block (LDS-cached)
#define MAXNR 160     // max graph node-rows staged in LDS (fallback above)

// ---------------- Phase A: GEMM y = x@w_pre + b_pre (f16) + col stats; fused wprime + hist + pbuf-zero ----------------
__global__ __launch_bounds__(256) void k_pre_gemm(const float* __restrict__ x,
        const float* __restrict__ w_pre, const float* __restrict__ b_pre,
        f16_t* __restrict__ y, float* __restrict__ stats, int N,
        const float* __restrict__ w_cn, bf16_t* __restrict__ wpT,
        const int* __restrict__ src, const int* __restrict__ seg,
        int* __restrict__ gcnt, int E, float* __restrict__ pzero) {
    __shared__ float ws[64][128];
    __shared__ float xs[64][64];
    __shared__ float red[8][2][128];
    __shared__ int lh[512];
    const int tid = threadIdx.x;
    const int row0 = blockIdx.x * 64;

    // fused pbuf zero: blocks 0..255 clear 512*128 floats (agg runs 3 dispatches later)
    if (blockIdx.x < 256) pzero[blockIdx.x * 256 + tid] = 0.f;

    for (int i = tid; i < 64 * 128; i += 256) ws[i >> 7][i & 127] = w_pre[i];
    {
        int r = tid >> 2, q = tid & 3;
        int rg = row0 + r; if (rg >= N) rg = N - 1;
        const float4* xr = (const float4*)(x + (size_t)rg * 64 + q * 16);
        float4* dr = (float4*)(&xs[r][q * 16]);
#pragma unroll
        for (int j = 0; j < 4; ++j) dr[j] = xr[j];
    }
    __syncthreads();

    const int rg8 = tid >> 5;
    const int c0 = (tid & 31) * 4;
    float acc[8][4] = {};
    for (int k = 0; k < 64; ++k) {
        float4 wv = *(const float4*)(&ws[k][c0]);
#pragma unroll
        for (int i = 0; i < 8; ++i) {
            float xv = xs[rg8 * 8 + i][k];
            acc[i][0] += xv * wv.x;
            acc[i][1] += xv * wv.y;
            acc[i][2] += xv * wv.z;
            acc[i][3] += xv * wv.w;
        }
    }

    float bc[4];
#pragma unroll
    for (int j = 0; j < 4; ++j) bc[j] = b_pre[c0 + j];
    float s1[4] = {}, s2[4] = {};
#pragma unroll
    for (int i = 0; i < 8; ++i) {
        int row = row0 + rg8 * 8 + i;
        if (row < N) {
            f16x4 o;
#pragma unroll
            for (int j = 0; j < 4; ++j) {
                float yv = acc[i][j] + bc[j];
                o[j] = (f16_t)yv;
                s1[j] += yv; s2[j] += yv * yv;
            }
            *(f16x4*)(y + (size_t)row * 128 + c0) = o;
        }
    }
#pragma unroll
    for (int j = 0; j < 4; ++j) {
        red[rg8][0][c0 + j] = s1[j];
        red[rg8][1][c0 + j] = s2[j];
    }
    __syncthreads();
    {
        int col = tid & 127, st = tid >> 7;
        float t = 0.f;
#pragma unroll
        for (int g = 0; g < 8; ++g) t += red[g][st][col];
        atomicAdd(&stats[st * 128 + col], t);
    }

    // fused wprime: blocks 0..127 build wpT[n][k]
    if (blockIdx.x < 128) {
        int k = blockIdx.x;
        int c = tid & 127, half = tid >> 7;
        if (half == 0)
            wpT[c * 128 + k] = (bf16_t)(w_cn[k * 128 + c] - w_cn[(128 + k) * 128 + c]);
        else
            wpT[(128 + c) * 128 + k] = (bf16_t)(w_cn[(128 + k) * 128 + c]);
    }

    // fused hist: grid-stride histogram of g = seg[src[e]]
    for (int i = tid; i < 512; i += 256) lh[i] = 0;
    __syncthreads();
    for (int e = blockIdx.x * 256 + tid; e < E; e += gridDim.x * 256)
        atomicAdd(&lh[seg[src[e]]], 1);
    __syncthreads();
    for (int i = tid; i < 512; i += 256)
        if (lh[i]) atomicAdd(&gcnt[i], lh[i]);
}

// ---------------- k_uv: BN folded from stats; [u|v] = h @ W' -> pair-major f16 [4][N][32] ----------------
__global__ __launch_bounds__(256) void k_uv(const f16_t* __restrict__ ypre,
        const float* __restrict__ stats, const float* __restrict__ g_pre,
        const float* __restrict__ be_pre, const bf16_t* __restrict__ wpT,
        const float* __restrict__ b_cn,
        f16_t* __restrict__ u, f16_t* __restrict__ v, int N, int ntiles, float invN) {
    __shared__ bf16_t at[64 * 136];
    __shared__ f16_t ot[64 * 264];
    __shared__ float a_s[128], b_s[128];

    const int tid = threadIdx.x;
    const int lane = tid & 63;
    const int wv = tid >> 6;
    const int n0 = wv * 64;
    const int l16 = lane & 15;
    const int lg = lane >> 4;

    if (tid < 128) {
        float mu = stats[tid] * invN;
        float var = stats[128 + tid] * invN - mu * mu;
        float a = g_pre[tid] * rsqrtf(var + 1e-3f);
        a_s[tid] = a;
        b_s[tid] = be_pre[tid] - mu * a;
    }

    bf16x8 bfr[4][4];
#pragma unroll
    for (int s = 0; s < 4; ++s)
#pragma unroll
        for (int c = 0; c < 4; ++c)
            bfr[s][c] = *(const bf16x8*)(wpT + (n0 + 16 * c + l16) * 128 + 32 * s + 8 * lg);

    float bias[4];
#pragma unroll
    for (int c = 0; c < 4; ++c) {
        int n = n0 + 16 * c + l16;
        bias[c] = (n < 128) ? b_cn[n] : 0.f;
    }

    const int sr = tid >> 2, sq = tid & 3;
    __syncthreads();   // a_s/b_s ready before first staging

    for (int tile = blockIdx.x; tile < ntiles; tile += gridDim.x) {
        const int row0 = tile * 64;
        {
            int rg = row0 + sr; if (rg >= N) rg = N - 1;
            const f16_t* yr = ypre + (size_t)rg * 128 + sq * 32;
            bf16_t* dr = at + sr * 136 + sq * 32;
#pragma unroll
            for (int c4 = 0; c4 < 4; ++c4) {
                f16x8 yv = *(const f16x8*)(yr + c4 * 8);
                bf16x8 hv;
#pragma unroll
                for (int j = 0; j < 8; ++j) {
                    int col = sq * 32 + c4 * 8 + j;
                    hv[j] = (bf16_t)fmaxf(a_s[col] * (float)yv[j] + b_s[col], 0.f);
                }
                *(bf16x8*)(dr + c4 * 8) = hv;
            }
        }
        __syncthreads();

        f32x4 acc[4][4];
#pragma unroll
        for (int c = 0; c < 4; ++c) {
            f32x4 ini = {bias[c], bias[c], bias[c], bias[c]};
#pragma unroll
            for (int rt = 0; rt < 4; ++rt) acc[rt][c] = ini;
        }
#pragma unroll
        for (int s = 0; s < 4; ++s) {
            bf16x8 afr[4];
#pragma unroll
            for (int rt = 0; rt < 4; ++rt)
                afr[rt] = *(const bf16x8*)(at + (rt * 16 + l16) * 136 + 32 * s + 8 * lg);
#pragma unroll
            for (int rt = 0; rt < 4; ++rt)
#pragma unroll
                for (int c = 0; c < 4; ++c)
                    acc[rt][c] = __builtin_amdgcn_mfma_f32_16x16x32_bf16(afr[rt], bfr[s][c], acc[rt][c], 0, 0, 0);
        }

#pragma unroll
        for (int rt = 0; rt < 4; ++rt)
#pragma unroll
            for (int c = 0; c < 4; ++c) {
                int n = n0 + 16 * c + l16;
#pragma unroll
                for (int reg = 0; reg < 4; ++reg) {
                    int r = rt * 16 + lg * 4 + reg;
                    ot[r * 264 + n] = (f16_t)acc[rt][c][reg];
                }
            }
        __syncthreads();

        // copy out to pair-major [4][N][32]
#pragma unroll
        for (int it = 0; it < 8; ++it) {
            int r = wv * 16 + it * 2 + (lane >> 5);
            int cc = (lane & 31) * 8;
            int rg = row0 + r;
            if (rg < N) {
                f16x8 w8 = *(const f16x8*)(ot + r * 264 + cc);
                if (cc < 128) {
                    int sp = cc >> 5, col = cc & 31;
                    *(f16x8*)(u + ((size_t)sp * N + rg) * 32 + col) = w8;
                } else {
                    int cv = cc - 128;
                    int sp = cv >> 5, col = cv & 31;
                    *(f16x8*)(v + ((size_t)sp * N + rg) * 32 + col) = w8;
                }
            }
        }
    }
}

// ---------------- k_scatter (+ fused scan + nodeoff): one pass, LDS-cached, u32-packed ----------------
__global__ __launch_bounds__(512) void k_scatter(const int* __restrict__ src,
        const int* __restrict__ dst, const int* __restrict__ seg,
        int* __restrict__ cursor, unsigned int* __restrict__ sorted, int E, int CH,
        int* __restrict__ node_off, int N, int G,
        const int* __restrict__ gcnt, int* __restrict__ offs) {
    __shared__ int pref[512];
    __shared__ int lh[512];
    __shared__ int lbase[512];
    __shared__ unsigned int pcache[SC_CAP];
    __shared__ unsigned short gcache[SC_CAP];
    const int tid = threadIdx.x;

    // fused scan of gcnt (every block computes it; block 0 publishes offs)
    int gc = gcnt[tid];
    pref[tid] = gc;
    __syncthreads();
    for (int off = 1; off < 512; off <<= 1) {
        int vv = (tid >= off) ? pref[tid - off] : 0;
        __syncthreads();
        pref[tid] += vv;
        __syncthreads();
    }
    if (blockIdx.x == 0) {
        offs[tid + 1] = pref[tid];
        if (tid == 0) offs[0] = 0;
    }
    const int excl = pref[tid] - gc;

    // fused nodeoff: node_off[g] = first node row of graph g (seg sorted)
    {
        int i = blockIdx.x * 512 + tid;
        if (i < N) {
            int s = seg[i];
            int prev = (i == 0) ? -1 : seg[i - 1];
            for (int g2 = prev + 1; g2 <= s; ++g2) node_off[g2] = i;
            if (i == N - 1)
                for (int g2 = s + 1; g2 <= G; ++g2) node_off[g2] = N;
        }
    }

    const int e0 = blockIdx.x * CH;
    const int e1 = min(E, e0 + CH);
    lh[tid] = 0;
    __syncthreads();
    for (int e = e0 + tid; e < e1; e += 512) {
        int si = src[e], di = dst[e];
        int g = seg[si];
        pcache[e - e0] = ((unsigned)si << 16) | (unsigned)di;
        gcache[e - e0] = (unsigned short)g;
        atomicAdd(&lh[g], 1);
    }
    __syncthreads();
    {
        int c = lh[tid];
        lbase[tid] = c ? (excl + atomicAdd(&cursor[tid], c)) : 0;
        lh[tid] = 0;
    }
    __syncthreads();
    for (int e = e0 + tid; e < e1; e += 512) {
        int g = gcache[e - e0];
        int k = atomicAdd(&lh[g], 1);
        sorted[lbase[g] + k] = pcache[e - e0];
    }
}

// ---------------- k_agg_pair: block (g, sp, span); 32-col pair-slice, 2 edge-spans, 4 streams ----------------
// sp = (bid&7)>>1 -> pair sp pinned to XCDs {2sp,2sp+1}; v-pair (3.2MB) L2-resident.
// v-row slice = 64B read by 4 consecutive lanes -> fully coalesced segments.
// u staged in LDS (stride 40 f16 = 80B). 4 independent streams double in-flight misses.
__global__ __launch_bounds__(256) void k_agg_pair(const unsigned int* __restrict__ sorted,
        const int* __restrict__ offs, const int* __restrict__ node_off,
        const f16_t* __restrict__ u, const f16_t* __restrict__ v,
        float* __restrict__ p, int N) {
    const int bid = blockIdx.x;
    const int sp = (bid & 7) >> 1;
    const int span = (bid >> 3) & 1;
    const int g = (bid >> 4) * 2 + (bid & 1);
    const int s0 = offs[g], s1 = offs[g + 1];
    const int r0 = node_off[g];
    const int nr = node_off[g + 1] - r0;
    const int tid = threadIdx.x;
    const int lane = tid & 63;
    const int wv = tid >> 6;
    const int eidx = lane >> 2;        // 16 edges per wave-chunk
    const int c0 = (lane & 3) * 8;     // 8 cols per lane (4 lanes cover 32 cols = 64B)
    const f16_t* ug = u + (size_t)sp * N * 32;
    const f16_t* vg = v + (size_t)sp * N * 32;
    const f16x8 zero = {};
    float acc[8] = {};

    __shared__ f16_t ulds[MAXNR * 40];   // row stride 40 f16 = 80B
    __shared__ float red[4][4][8];

    if (nr <= MAXNR) {
        // stage u rows [r0, r0+nr) x 32 cols: contiguous global -> LDS, coalesced
        for (int i = tid; i < nr * 4; i += 256) {
            int row = i >> 2, q = i & 3;
            *(f16x8*)(ulds + row * 40 + q * 8) =
                *(const f16x8*)(ug + (size_t)(r0 + row) * 32 + q * 8);
        }
        __syncthreads();

        int base = s0 + (span * 4 + wv) * 16;
        for (; base + 400 <= s1; base += 512) {   // 4 streams, unguarded
            unsigned pA = sorted[base + eidx];
            unsigned pB = sorted[base + 128 + eidx];
            unsigned pC = sorted[base + 256 + eidx];
            unsigned pD = sorted[base + 384 + eidx];
            f16x8 vA = *(const f16x8*)(vg + (size_t)(pA & 0xffffu) * 32 + c0);
            f16x8 vB = *(const f16x8*)(vg + (size_t)(pB & 0xffffu) * 32 + c0);
            f16x8 vC = *(const f16x8*)(vg + (size_t)(pC & 0xffffu) * 32 + c0);
            f16x8 vD = *(const f16x8*)(vg + (size_t)(pD & 0xffffu) * 32 + c0);
            f16x8 uA = *(const f16x8*)(ulds + ((int)(pA >> 16) - r0) * 40 + c0);
            f16x8 uB = *(const f16x8*)(ulds + ((int)(pB >> 16) - r0) * 40 + c0);
            f16x8 uC = *(const f16x8*)(ulds + ((int)(pC >> 16) - r0) * 40 + c0);
            f16x8 uD = *(const f16x8*)(ulds + ((int)(pD >> 16) - r0) * 40 + c0);
            f16x8 rA = __builtin_elementwise_max(uA + vA, zero);
            f16x8 rB = __builtin_elementwise_max(uB + vB, zero);
            f16x8 rC = __builtin_elementwise_max(uC + vC, zero);
            f16x8 rD = __builtin_elementwise_max(uD + vD, zero);
#pragma unroll
            for (int j = 0; j < 8; ++j) acc[j] += (float)rA[j];
#pragma unroll
            for (int j = 0; j < 8; ++j) acc[j] += (float)rB[j];
#pragma unroll
            for (int j = 0; j < 8; ++j) acc[j] += (float)rC[j];
#pragma unroll
            for (int j = 0; j < 8; ++j) acc[j] += (float)rD[j];
        }
        for (; base < s1; base += 128) {          // guarded tail
            int e = base + eidx;
            if (e < s1) {
                unsigned pk = sorted[e];
                f16x8 vv = *(const f16x8*)(vg + (size_t)(pk & 0xffffu) * 32 + c0);
                f16x8 uu = *(const f16x8*)(ulds + ((int)(pk >> 16) - r0) * 40 + c0);
                f16x8 r = __builtin_elementwise_max(uu + vv, zero);
#pragma unroll
                for (int j = 0; j < 8; ++j) acc[j] += (float)r[j];
            }
        }
    } else {
        // fallback: global u gather (also 64B-coalesced), 2 streams
        int base = s0 + (span * 4 + wv) * 16;
        for (; base + 144 <= s1; base += 256) {
            unsigned pA = sorted[base + eidx];
            unsigned pB = sorted[base + 128 + eidx];
            f16x8 uA = *(const f16x8*)(ug + (size_t)(pA >> 16) * 32 + c0);
            f16x8 vA = *(const f16x8*)(vg + (size_t)(pA & 0xffffu) * 32 + c0);
            f16x8 uB = *(const f16x8*)(ug + (size_t)(pB >> 16) * 32 + c0);
            f16x8 vB = *(const f16x8*)(vg + (size_t)(pB & 0xffffu) * 32 + c0);
            f16x8 rA = __builtin_elementwise_max(uA + vA, zero);
            f16x8 rB = __builtin_elementwise_max(uB + vB, zero);
#pragma unroll
            for (int j = 0; j < 8; ++j) acc[j] += (float)rA[j];
#pragma unroll
            for (int j = 0; j < 8; ++j) acc[j] += (float)rB[j];
        }
        for (; base < s1; base += 128) {
            int e = base + eidx;
            if (e < s1) {
                unsigned pk = sorted[e];
                f16x8 uu = *(const f16x8*)(ug + (size_t)(pk >> 16) * 32 + c0);
                f16x8 vv = *(const f16x8*)(vg + (size_t)(pk & 0xffffu) * 32 + c0);
                f16x8 r = __builtin_elementwise_max(uu + vv, zero);
#pragma unroll
                for (int j = 0; j < 8; ++j) acc[j] += (float)r[j];
            }
        }
    }

    // reduce across the 16 edge-groups (lane bits 2..5)
#pragma unroll
    for (int j = 0; j < 8; ++j) {
        acc[j] += __shfl_xor(acc[j], 4, 64);
        acc[j] += __shfl_xor(acc[j], 8, 64);
        acc[j] += __shfl_xor(acc[j], 16, 64);
        acc[j] += __shfl_xor(acc[j], 32, 64);
    }
    if (lane < 4) {
#pragma unroll
        for (int j = 0; j < 8; ++j) red[wv][lane][j] = acc[j];
    }
    __syncthreads();
    if (tid < 32) {
        int cs = tid >> 3, j = tid & 7;
        float sum = red[0][cs][j] + red[1][cs][j] + red[2][cs][j] + red[3][cs][j];
        atomicAdd(&p[g * 128 + sp * 32 + cs * 8 + j], sum);
    }
}

// ---------------- Phase C: post MLP + BN + head ----------------
__global__ __launch_bounds__(256) void k_post_gemm(const float* __restrict__ p,
        const float* __restrict__ w_post, const float* __restrict__ b_post,
        float* __restrict__ y, float* __restrict__ stats) {
    int tid = threadIdx.x;
    int row0 = blockIdx.x * 16;
    int col = tid & 127, rg = tid >> 7;
    float acc[8] = {};
    for (int k = 0; k < 128; ++k) {
        float wv = w_post[k * 128 + col];
#pragma unroll
        for (int i = 0; i < 8; ++i) acc[i] += p[(row0 + rg * 8 + i) * 128 + k] * wv;
    }
    float b = b_post[col], s1 = 0.f, s2 = 0.f;
#pragma unroll
    for (int i = 0; i < 8; ++i) {
        float yv = acc[i] + b;
        y[(row0 + rg * 8 + i) * 128 + col] = yv;
        s1 += yv; s2 += yv * yv;
    }
    atomicAdd(&stats[col], s1);
    atomicAdd(&stats[128 + col], s2);
}

__global__ __launch_bounds__(256) void k_out(const float* __restrict__ y,
        const float* __restrict__ stats, const float* __restrict__ g_post,
        const float* __restrict__ be_post, const float* __restrict__ w_out,
        const float* __restrict__ b_out, float* __restrict__ out, float invG) {
    __shared__ float a_s[128], b_s[128];
    int tid = threadIdx.x;
    if (tid < 128) {
        float mu = stats[tid] * invG;
        float var = stats[128 + tid] * invG - mu * mu;
        float a = g_post[tid] * rsqrtf(var + 1e-3f);
        a_s[tid] = a;
        b_s[tid] = be_post[tid] - mu * a;
    }
    __syncthreads();
    int lane = tid & 63;
    int wv = tid >> 6;
    int row = blockIdx.x * 4 + wv;
    int c0 = lane * 2;
    float v = 0.f;
#pragma unroll
    for (int j = 0; j < 2; ++j) {
        int c = c0 + j;
        float t = fmaxf(a_s[c] * y[row * 128 + c] + b_s[c], 0.f);
        v += t * w_out[c];
    }
#pragma unroll
    for (int m = 32; m >= 1; m >>= 1) v += __shfl_xor(v, m, 64);
    if (lane == 0) out[row] = 1.f / (1.f + expf(-(v + b_out[0])));
}

extern "C" void kernel_launch(void* const* d_in, const int* in_sizes, int n_in,
                              void* d_out, int out_size, void* d_ws, size_t ws_size,
                              hipStream_t stream) {
    const float* x      = (const float*)d_in[0];
    const int*   src    = (const int*)d_in[1];
    const int*   dst    = (const int*)d_in[2];
    const int*   seg    = (const int*)d_in[3];
    const float* w_pre  = (const float*)d_in[4];
    const float* b_pre  = (const float*)d_in[5];
    const float* g_pre  = (const float*)d_in[6];
    const float* be_pre = (const float*)d_in[7];
    const float* w_cn   = (const float*)d_in[8];
    const float* b_cn   = (const float*)d_in[9];
    const float* w_post = (const float*)d_in[10];
    const float* b_post = (const float*)d_in[11];
    const float* g_post = (const float*)d_in[12];
    const float* be_post= (const float*)d_in[13];
    const float* w_out  = (const float*)d_in[14];
    const float* b_out  = (const float*)d_in[15];
    const int E = in_sizes[1];
    const int N = in_sizes[3];
    const int G = out_size;

    char* ws = (char*)d_ws;
    float* stats_pre  = (float*)(ws + 0);        // zeroed each call
    float* stats_post = (float*)(ws + 1024);     // zeroed each call
    int*   gcnt       = (int*)(ws + 2048);       // zeroed each call
    int*   offs       = (int*)(ws + 4096);       // 513 ints (written by scatter blk 0)
    int*   cursor     = (int*)(ws + 8192);       // 512 ints, zeroed each call
    int*   node_off   = (int*)(ws + 10240);      // 513 ints
    bf16_t* wpT       = (bf16_t*)(ws + 16384);   // 64KB
    float* pbuf       = (float*)(ws + 131072);   // 256KB, zeroed by k_pre_gemm blocks 0..255
    float* ybuf       = (float*)(ws + 131072 + 262144);
    size_t big0 = 1 << 20;
    size_t NB = (((size_t)N * 128 * 2) + 4095) & ~(size_t)4095;
    f16_t* ubuf = (f16_t*)(ws + big0);            // [4][N][32] f16
    f16_t* vbuf = (f16_t*)(ws + big0 + NB);       // [4][N][32] f16
    unsigned int* sorted = (unsigned int*)(ws + big0 + 2 * NB);
    f16_t* ypre  = (f16_t*)(ws + big0 + 3 * NB);
    (void)ws_size;

    // zero stats/gcnt/cursor (pbuf zeroed inside k_pre_gemm)
    (void)hipMemsetAsync(ws, 0, 10240, stream);

    int nb64 = (N + 63) / 64;
    k_pre_gemm<<<nb64, 256, 0, stream>>>(x, w_pre, b_pre, ypre, stats_pre, N,
                                         w_cn, wpT, src, seg, gcnt, E, pbuf);
    k_uv<<<nb64, 256, 0, stream>>>(ypre, stats_pre, g_pre, be_pre, wpT, b_cn,
                                   ubuf, vbuf, N, nb64, 1.f / (float)N);
    int nsc = (E + SC_CAP - 1) / SC_CAP;
    k_scatter<<<nsc, 512, 0, stream>>>(src, dst, seg, cursor, sorted, E, SC_CAP,
                                       node_off, N, G, gcnt, offs);
    k_agg_pair<<<16 * (G / 2), 256, 0, stream>>>(sorted, offs, node_off, ubuf, vbuf, pbuf, N);
    k_post_gemm<<<G / 16, 256, 0, stream>>>(pbuf, w_post, b_post, ybuf, stats_post);
    k_out<<<G / 4, 256, 0, stream>>>(ybuf, stats_post, g_post, be_post, w_out, b_out,
                                     (float*)d_out, 1.f / (float)G);
}